// Round 4
// baseline (1331.028 us; speedup 1.0000x reference)
//
#include <hip/hip_runtime.h>
#include <hip/hip_bf16.h>

// SlotMamba: B=64, K=256, D_MODEL=512, D_INNER=512, D_STATE=16, D_CONV=4, DT_RANK=32
// NTOK = B*K = 16384 tokens.
// Inputs: float32. Output: float32. Compute in f32.
//
// ws layout (f32 elements), N1 = 16384*512 = 8388608. Total 98 MiB.
//   regA [0 , N1)   xln (LN out) -> dead after k_inproj -> dt (k_xproj) -> ya (k_scan, in-place)
//   xi   [N1, 2N1)  in_proj x-half (conv input, conv recomputed on the fly by consumers)
//   zs   [2N1,3N1)  silu(z)
//   Bc   [3N1, +16384*16), Cc next 16384*16

#define NTOK 16384
#define DM   512

__device__ __forceinline__ float silu(float a){ return a / (1.f + __expf(-a)); }

// ---------------- K1: LayerNorm(slots) -> xln (f32) -------------------------
__global__ __launch_bounds__(64) void k_ln(const float* __restrict__ x,
                                           const float* __restrict__ g,
                                           const float* __restrict__ b,
                                           float* __restrict__ out){
  int tok  = blockIdx.x;
  int lane = threadIdx.x;
  const float* row = x + (size_t)tok*DM + lane*8;
  float4 r0 = *(const float4*)row;
  float4 r1 = *(const float4*)(row + 4);
  float v[8] = {r0.x,r0.y,r0.z,r0.w, r1.x,r1.y,r1.z,r1.w};
  float s = 0.f;
  #pragma unroll
  for (int i=0;i<8;i++) s += v[i];
  #pragma unroll
  for (int o=32;o;o>>=1) s += __shfl_xor(s, o, 64);
  float m = s * (1.0f/512.0f);
  float vs = 0.f;
  #pragma unroll
  for (int i=0;i<8;i++){ float d = v[i]-m; vs += d*d; }
  #pragma unroll
  for (int o=32;o;o>>=1) vs += __shfl_xor(vs, o, 64);
  float rs = rsqrtf(vs*(1.0f/512.0f) + 1e-5f);
  float4 g0 = *(const float4*)(g + lane*8);
  float4 g1 = *(const float4*)(g + lane*8 + 4);
  float4 b0 = *(const float4*)(b + lane*8);
  float4 b1 = *(const float4*)(b + lane*8 + 4);
  float gv[8] = {g0.x,g0.y,g0.z,g0.w, g1.x,g1.y,g1.z,g1.w};
  float bv[8] = {b0.x,b0.y,b0.z,b0.w, b1.x,b1.y,b1.z,b1.w};
  float o8[8];
  #pragma unroll
  for (int i=0;i<8;i++) o8[i] = (v[i]-m)*rs*gv[i] + bv[i];
  float4* op = (float4*)(out + (size_t)tok*DM + lane*8);
  op[0] = make_float4(o8[0],o8[1],o8[2],o8[3]);
  op[1] = make_float4(o8[4],o8[5],o8[6],o8[7]);
}

// ---------------- K2: xz = xln @ in_proj_w.T ; xi, zs=silu(z) ---------------
__global__ __launch_bounds__(256) void k_inproj(const float* __restrict__ xln,
                                                const float* __restrict__ W,
                                                float* __restrict__ xi,
                                                float* __restrict__ zs){
  __shared__ __align__(16) float xs[16*DM];
  int t0  = blockIdx.x * 16;
  int tid = threadIdx.x;
  for (int i=tid; i<16*DM; i+=256) xs[i] = xln[(size_t)t0*DM + i];
  __syncthreads();

  float acc[4][16];
  #pragma unroll
  for (int j=0;j<4;j++)
    #pragma unroll
    for (int t=0;t<16;t++) acc[j][t] = 0.f;

  const float* wr[4];
  #pragma unroll
  for (int j=0;j<4;j++) wr[j] = W + (size_t)(tid + 256*j)*DM;

  for (int k=0;k<DM;k+=4){
    float4 w[4];
    #pragma unroll
    for (int j=0;j<4;j++) w[j] = *(const float4*)(wr[j] + k);
    #pragma unroll
    for (int h=0;h<2;h++){
      float4 xv[8];
      #pragma unroll
      for (int i=0;i<8;i++) xv[i] = *(const float4*)&xs[(h*8+i)*DM + k];
      #pragma unroll
      for (int j=0;j<4;j++)
        #pragma unroll
        for (int i=0;i<8;i++){
          float a = acc[j][h*8+i];
          a += xv[i].x*w[j].x;
          a += xv[i].y*w[j].y;
          a += xv[i].z*w[j].z;
          a += xv[i].w*w[j].w;
          acc[j][h*8+i] = a;
        }
    }
  }

  #pragma unroll
  for (int j=0;j<4;j++){
    int nn = tid + 256*j;
    #pragma unroll
    for (int t=0;t<16;t++){
      float a = acc[j][t];
      size_t off = (size_t)(t0+t)*DM;
      if (j < 2) xi[off + nn] = a;
      else       zs[off + nn - 512] = silu(a);
    }
  }
}

// -------- K3: conv4+silu (on the fly) ; proj = xc @ x_proj_w.T ; dt ---------
__global__ __launch_bounds__(256) void k_xproj(const float* __restrict__ xi,
                                               const float* __restrict__ cw,
                                               const float* __restrict__ cb,
                                               const float* __restrict__ xpw,
                                               const float* __restrict__ dtw,
                                               const float* __restrict__ dtb,
                                               float* __restrict__ dt,
                                               float* __restrict__ Bc,
                                               float* __restrict__ Cc){
  __shared__ __align__(16) float xs[16*DM];
  __shared__ __align__(16) float pj[16*64];
  int t0  = blockIdx.x * 16;
  int tid = threadIdx.x;

  // causal depthwise conv4 + silu -> xs (xc tile)
  #pragma unroll
  for (int j=0;j<2;j++){
    int d = tid + 256*j;
    float4 cr = *(const float4*)(cw + d*4);
    float a0 = cb[d];
    for (int t=0;t<16;t++){
      int tl = (t0 + t) & 255;                 // position within the 256-token sequence
      const float* p = xi + (size_t)(t0+t)*DM + d;
      float a = a0 + p[0]*cr.w;
      if (tl >= 1) a += p[-DM]*cr.z;
      if (tl >= 2) a += p[-2*DM]*cr.y;
      if (tl >= 3) a += p[-3*DM]*cr.x;
      xs[t*DM + d] = silu(a);
    }
  }
  __syncthreads();

  // proj: 64 outputs x 16 tokens; thread (n = tid&63) handles token group tid>>6
  int n = tid & 63, grp = tid >> 6;
  const float* wr = xpw + (size_t)n*DM;
  float a[4] = {0.f,0.f,0.f,0.f};
  for (int k=0;k<DM;k+=4){
    float4 w4 = *(const float4*)(wr + k);
    #pragma unroll
    for (int q=0;q<4;q++){
      float4 xv = *(const float4*)&xs[(grp*4+q)*DM + k];
      a[q] += xv.x*w4.x + xv.y*w4.y + xv.z*w4.z + xv.w*w4.w;
    }
  }
  #pragma unroll
  for (int q=0;q<4;q++) pj[(grp*4+q)*64 + n] = a[q];
  __syncthreads();

  // B, C extraction
  for (int i=tid; i<16*32; i+=256){
    int tt = i >> 5, c = i & 31;
    float v = pj[tt*64 + 32 + c];
    if (c < 16) Bc[(size_t)(t0+tt)*16 + c]      = v;
    else        Cc[(size_t)(t0+tt)*16 + (c-16)] = v;
  }

  // dt: 512 outputs, thread handles nn = tid, tid+256 over all 16 tokens
  #pragma unroll
  for (int jn=0;jn<2;jn++){
    int nn = tid + 256*jn;
    const float* dr = dtw + (size_t)nn*32;
    float wv[32];
    #pragma unroll
    for (int r=0;r<32;r+=4){
      float4 t4 = *(const float4*)(dr + r);
      wv[r]=t4.x; wv[r+1]=t4.y; wv[r+2]=t4.z; wv[r+3]=t4.w;
    }
    float bb = dtb[nn];
    for (int tt=0;tt<16;tt++){
      const float* pr = &pj[tt*64];
      float s = bb;
      #pragma unroll
      for (int r=0;r<32;r++) s += pr[r]*wv[r];
      float sp = (s > 20.f) ? s : log1pf(__expf(s));   // softplus
      dt[(size_t)(t0+tt)*DM + nn] = sp;
    }
  }
}

// ------ K4: selective scan (conv on the fly) -> ya = (y + xc*Dp)*zs ---------
// dtya holds dt on entry; overwritten in place with ya (read-before-write,
// one thread owns each address). NOT __restrict__ (intentional alias).
__global__ __launch_bounds__(64) void k_scan(float* dtya,
                                             const float* __restrict__ xi,
                                             const float* __restrict__ zs,
                                             const float* __restrict__ Bc,
                                             const float* __restrict__ Cc,
                                             const float* __restrict__ cw,
                                             const float* __restrict__ cb,
                                             const float* __restrict__ Alog,
                                             const float* __restrict__ Dpw){
  int gid = blockIdx.x*64 + threadIdx.x;   // 0..32767  (b,d)
  int d = gid & 511;
  int b = gid >> 9;
  float A[16];
  #pragma unroll
  for (int s=0;s<16;s++) A[s] = -__expf(Alog[d*16 + s]);
  float Dv = Dpw[d];
  float4 cr = *(const float4*)(cw + d*4);
  float cbv = cb[d];
  float h[16];
  #pragma unroll
  for (int s=0;s<16;s++) h[s] = 0.f;
  float xm1=0.f, xm2=0.f, xm3=0.f;
  size_t base = (size_t)b*256*DM + d;
  const float* xip = xi   + base;
  const float* zsp = zs   + base;
  float*       dyp = dtya + base;
  const float* Bp  = Bc + (size_t)b*256*16;
  const float* Cp  = Cc + (size_t)b*256*16;
  for (int t=0;t<256;t++){
    float xt = xip[t*DM];
    float a  = cbv + xm3*cr.x + xm2*cr.y + xm1*cr.z + xt*cr.w;
    float u  = silu(a);
    float dv = dyp[t*DM];            // read dt BEFORE writing ya (same addr)
    float du = dv*u;
    float y  = 0.f;
    #pragma unroll
    for (int s=0;s<16;s++){
      float dA = __expf(dv*A[s]);
      h[s] = dA*h[s] + du*Bp[t*16+s];
      y   += h[s]*Cp[t*16+s];
    }
    dyp[t*DM] = (y + u*Dv) * zsp[t*DM];
    xm3 = xm2; xm2 = xm1; xm1 = xt;
  }
}

// ---------------- K5: o = ya @ out_proj_w.T + slots ; final LN -> out (f32)
__global__ __launch_bounds__(256) void k_out(const float* __restrict__ ya,
                                             const float* __restrict__ W,
                                             const float* __restrict__ res,
                                             const float* __restrict__ fg,
                                             const float* __restrict__ fb,
                                             float* __restrict__ out){
  __shared__ __align__(16) float xs[16*DM];   // ya tile, reused for o-tile
  __shared__ float stats[32];
  int t0  = blockIdx.x * 16;
  int tid = threadIdx.x;
  for (int i=tid; i<16*DM; i+=256) xs[i] = ya[(size_t)t0*DM + i];
  __syncthreads();

  float acc[2][16];
  #pragma unroll
  for (int j=0;j<2;j++)
    #pragma unroll
    for (int t=0;t<16;t++) acc[j][t] = 0.f;

  const float* wr0 = W + (size_t)tid*DM;
  const float* wr1 = W + (size_t)(tid+256)*DM;
  for (int k=0;k<DM;k+=4){
    float4 wa = *(const float4*)(wr0 + k);
    float4 wb = *(const float4*)(wr1 + k);
    #pragma unroll
    for (int h=0;h<2;h++){
      float4 xv[8];
      #pragma unroll
      for (int i=0;i<8;i++) xv[i] = *(const float4*)&xs[(h*8+i)*DM + k];
      #pragma unroll
      for (int i=0;i<8;i++){
        float u0 = acc[0][h*8+i];
        u0 += xv[i].x*wa.x; u0 += xv[i].y*wa.y; u0 += xv[i].z*wa.z; u0 += xv[i].w*wa.w;
        acc[0][h*8+i] = u0;
        float u1 = acc[1][h*8+i];
        u1 += xv[i].x*wb.x; u1 += xv[i].y*wb.y; u1 += xv[i].z*wb.z; u1 += xv[i].w*wb.w;
        acc[1][h*8+i] = u1;
      }
    }
  }
  __syncthreads();   // done reading ya tile; reuse xs as o-tile

  #pragma unroll
  for (int j=0;j<2;j++){
    int nn = tid + 256*j;
    #pragma unroll
    for (int t=0;t<16;t++)
      xs[t*DM + nn] = acc[j][t] + res[(size_t)(t0+t)*DM + nn];
  }
  __syncthreads();

  // LN stats: 16 threads per token, lane l sums stride-16 elements
  int g = tid >> 4, l = tid & 15;
  float s = 0.f;
  #pragma unroll
  for (int i=0;i<32;i++) s += xs[g*DM + l + 16*i];
  #pragma unroll
  for (int o=8;o;o>>=1) s += __shfl_xor(s, o, 16);
  float m = s * (1.0f/512.0f);
  float vs = 0.f;
  #pragma unroll
  for (int i=0;i<32;i++){ float dd = xs[g*DM + l + 16*i] - m; vs += dd*dd; }
  #pragma unroll
  for (int o=8;o;o>>=1) vs += __shfl_xor(vs, o, 16);
  float rs = rsqrtf(vs*(1.0f/512.0f) + 1e-5f);
  if (l == 0){ stats[g*2] = m; stats[g*2+1] = rs; }
  __syncthreads();

  for (int i=tid; i<16*DM; i+=256){
    int tt = i >> 9, k = i & 511;
    out[(size_t)t0*DM + i] = (xs[i] - stats[tt*2]) * stats[tt*2+1] * fg[k] + fb[k];
  }
}

extern "C" void kernel_launch(void* const* d_in, const int* in_sizes, int n_in,
                              void* d_out, int out_size, void* d_ws, size_t ws_size,
                              hipStream_t stream) {
  const float* slots     = (const float*)d_in[0];
  const float* ln_g      = (const float*)d_in[1];
  const float* ln_b      = (const float*)d_in[2];
  const float* in_proj_w = (const float*)d_in[3];
  const float* conv_w    = (const float*)d_in[4];
  const float* conv_b    = (const float*)d_in[5];
  const float* x_proj_w  = (const float*)d_in[6];
  const float* dt_proj_w = (const float*)d_in[7];
  const float* dt_proj_b = (const float*)d_in[8];
  const float* A_log     = (const float*)d_in[9];
  const float* Dp        = (const float*)d_in[10];
  const float* out_projw = (const float*)d_in[11];
  const float* fln_g     = (const float*)d_in[12];
  const float* fln_b     = (const float*)d_in[13];
  float* out = (float*)d_out;

  float* ws = (float*)d_ws;
  const size_t N1 = (size_t)NTOK * DM;
  float* regA = ws;            // xln -> dt -> ya (aliased in place)
  float* xi   = ws + N1;
  float* zs   = ws + 2*N1;
  float* Bc   = ws + 3*N1;
  float* Cc   = Bc + (size_t)NTOK*16;

  k_ln    <<<NTOK,     64, 0, stream>>>(slots, ln_g, ln_b, regA);
  k_inproj<<<NTOK/16, 256, 0, stream>>>(regA, in_proj_w, xi, zs);
  k_xproj <<<NTOK/16, 256, 0, stream>>>(xi, conv_w, conv_b, x_proj_w, dt_proj_w, dt_proj_b,
                                        regA, Bc, Cc);
  k_scan  <<<512,      64, 0, stream>>>(regA, xi, zs, Bc, Cc, conv_w, conv_b, A_log, Dp);
  k_out   <<<NTOK/16, 256, 0, stream>>>(regA, out_projw, slots, fln_g, fln_b, out);
}

// Round 5
// 651.276 us; speedup vs baseline: 2.0437x; 2.0437x over previous
//
#include <hip/hip_runtime.h>
#include <hip/hip_bf16.h>

// SlotMamba: B=64, K=256, D_MODEL=512, D_INNER=512, D_STATE=16, D_CONV=4, DT_RANK=32
// NTOK = 16384 tokens. Inputs f32, output f32.
// GEMMs (in_proj 16384x1024x512, out_proj 16384x512x512) run as bf16 MFMA
// (16x16x32) with f32 accumulation; everything else stays f32.
//
// ws layout (bytes, MB = 2^20):       lifetime
//   xi    [0,  32MB) f32              k_gemm(in) -> k_xproj, k_scan
//   xlnb  [32, 48MB) bf16 (A of in)   k_ln -> k_gemm(in);  reused as yab: k_scan -> k_gemm(out)
//   zsb   [48, 64MB) bf16             k_gemm(in) -> k_scan
//   dt/o  [64, 96MB) f32              k_xproj -> k_scan;   reused as o: k_gemm(out) -> k_fln
//   Bc    [96, 97MB), Cc [97, 98MB)   k_xproj -> k_scan
// total 98 MiB (same footprint that passed in round 4).

#define NTOK 16384
#define DM   512

typedef __attribute__((ext_vector_type(8))) short bf16x8;   // 8 bf16 = 4 VGPRs
typedef __attribute__((ext_vector_type(4))) float f32x4;

__device__ __forceinline__ unsigned short f2bf(float f){
  unsigned int u = __float_as_uint(f);
  u = (u + 0x7fffu + ((u >> 16) & 1u)) >> 16;   // RNE
  return (unsigned short)u;
}
__device__ __forceinline__ float bfu(unsigned short p){ return __uint_as_float(((unsigned int)p) << 16); }
__device__ __forceinline__ unsigned int pk2(float a, float b){
  return (unsigned int)f2bf(a) | ((unsigned int)f2bf(b) << 16);
}
__device__ __forceinline__ float silu(float a){ return a / (1.f + __expf(-a)); }

// ---------------- K1: LayerNorm(slots) -> xlnb (bf16) -----------------------
__global__ __launch_bounds__(64) void k_ln(const float* __restrict__ x,
                                           const float* __restrict__ g,
                                           const float* __restrict__ b,
                                           unsigned short* __restrict__ out){
  int tok  = blockIdx.x;
  int lane = threadIdx.x;
  const float* row = x + (size_t)tok*DM + lane*8;
  float4 r0 = *(const float4*)row;
  float4 r1 = *(const float4*)(row + 4);
  float v[8] = {r0.x,r0.y,r0.z,r0.w, r1.x,r1.y,r1.z,r1.w};
  float s = 0.f;
  #pragma unroll
  for (int i=0;i<8;i++) s += v[i];
  #pragma unroll
  for (int o=32;o;o>>=1) s += __shfl_xor(s, o, 64);
  float m = s * (1.0f/512.0f);
  float vs = 0.f;
  #pragma unroll
  for (int i=0;i<8;i++){ float d = v[i]-m; vs += d*d; }
  #pragma unroll
  for (int o=32;o;o>>=1) vs += __shfl_xor(vs, o, 64);
  float rs = rsqrtf(vs*(1.0f/512.0f) + 1e-5f);
  float4 g0 = *(const float4*)(g + lane*8);
  float4 g1 = *(const float4*)(g + lane*8 + 4);
  float4 b0 = *(const float4*)(b + lane*8);
  float4 b1 = *(const float4*)(b + lane*8 + 4);
  float gv[8] = {g0.x,g0.y,g0.z,g0.w, g1.x,g1.y,g1.z,g1.w};
  float bv[8] = {b0.x,b0.y,b0.z,b0.w, b1.x,b1.y,b1.z,b1.w};
  float o8[8];
  #pragma unroll
  for (int i=0;i<8;i++) o8[i] = (v[i]-m)*rs*gv[i] + bv[i];
  uint4 st = { pk2(o8[0],o8[1]), pk2(o8[2],o8[3]), pk2(o8[4],o8[5]), pk2(o8[6],o8[7]) };
  *(uint4*)(out + (size_t)tok*DM + lane*8) = st;
}

// ---------------- K2: generic bf16-MFMA GEMM  C = A @ W^T -------------------
// A: [NTOK][512] bf16. W: [N][512] f32 (N = gridDim.y*128), cvt-staged to LDS.
// Block 256 thr = 4 waves; tile 32 tok x 128 cols; wave = 16 tok x 64 cols.
// mode 0 (in_proj): cols<512 -> xi f32 ; cols>=512 -> zsb = bf16(silu(z)).
// mode 1 (out_proj): plain f32 store.
__global__ __launch_bounds__(256) void k_gemm(const unsigned short* __restrict__ A,
                                              const float* __restrict__ W,
                                              float* __restrict__ out_f,
                                              unsigned short* __restrict__ out_b,
                                              int mode){
  __shared__ unsigned short As[32*520];   // +8 pad: 2-way-conflict-free frag reads
  __shared__ unsigned short Bs[128*40];   // per-K-step 128 x 32, +8 pad
  int t0  = blockIdx.x * 32;
  int n0  = blockIdx.y * 128;
  int tid = threadIdx.x;
  int lane = tid & 63;
  int wv  = tid >> 6;
  int mw  = wv >> 1, nw = wv & 1;

  // stage A tile (32 rows x 512 bf16), row stride 520
  for (int i = tid; i < 32*64; i += 256){
    int r = i >> 6, c = (i & 63) * 8;
    *(uint4*)&As[r*520 + c] = *(const uint4*)(A + (size_t)(t0+r)*DM + c);
  }

  f32x4 acc[4];
  #pragma unroll
  for (int j=0;j<4;j++) acc[j] = (f32x4){0.f,0.f,0.f,0.f};

  int n = tid >> 1, half = (tid & 1) * 16;      // thread stages W[n0+n][k0+half..+16]
  const float* wp = W + (size_t)(n0 + n)*DM + half;
  int m15 = lane & 15, quad = lane >> 4;

  for (int ks = 0; ks < 16; ks++){
    int k0 = ks * 32;
    float4 w0 = *(const float4*)(wp + k0);
    float4 w1 = *(const float4*)(wp + k0 + 4);
    float4 w2 = *(const float4*)(wp + k0 + 8);
    float4 w3 = *(const float4*)(wp + k0 + 12);
    __syncthreads();                             // prev step's reads done
    uint4 lo = { pk2(w0.x,w0.y), pk2(w0.z,w0.w), pk2(w1.x,w1.y), pk2(w1.z,w1.w) };
    uint4 hi = { pk2(w2.x,w2.y), pk2(w2.z,w2.w), pk2(w3.x,w3.y), pk2(w3.z,w3.w) };
    *(uint4*)&Bs[n*40 + half]     = lo;
    *(uint4*)&Bs[n*40 + half + 8] = hi;
    __syncthreads();                             // stage visible (covers As on ks=0)
    bf16x8 af = *(const bf16x8*)&As[(mw*16 + m15)*520 + k0 + quad*8];
    #pragma unroll
    for (int j=0;j<4;j++){
      bf16x8 bfr = *(const bf16x8*)&Bs[(nw*64 + j*16 + m15)*40 + quad*8];
      acc[j] = __builtin_amdgcn_mfma_f32_16x16x32_bf16(af, bfr, acc[j], 0, 0, 0);
    }
  }

  // epilogue: D row = quad*4+r (token), col = lane&15
  #pragma unroll
  for (int j=0;j<4;j++){
    int nn = n0 + nw*64 + j*16 + m15;
    #pragma unroll
    for (int r=0;r<4;r++){
      int tok = t0 + mw*16 + quad*4 + r;
      float v = acc[j][r];
      if (mode == 0){
        if (nn < DM) out_f[(size_t)tok*DM + nn] = v;
        else         out_b[(size_t)tok*DM + (nn - DM)] = f2bf(silu(v));
      } else {
        out_f[(size_t)tok*DM + nn] = v;
      }
    }
  }
}

// -------- K3: conv4+silu (on the fly) ; proj = xc @ x_proj_w.T ; dt ---------
__global__ __launch_bounds__(256) void k_xproj(const float* __restrict__ xi,
                                               const float* __restrict__ cw,
                                               const float* __restrict__ cb,
                                               const float* __restrict__ xpw,
                                               const float* __restrict__ dtw,
                                               const float* __restrict__ dtb,
                                               float* __restrict__ dt,
                                               float* __restrict__ Bc,
                                               float* __restrict__ Cc){
  __shared__ __align__(16) float xs[16*DM];
  __shared__ __align__(16) float pj[16*64];
  int t0  = blockIdx.x * 16;
  int tid = threadIdx.x;

  #pragma unroll
  for (int j=0;j<2;j++){
    int d = tid + 256*j;
    float4 cr = *(const float4*)(cw + d*4);
    float a0 = cb[d];
    for (int t=0;t<16;t++){
      int tl = (t0 + t) & 255;
      const float* p = xi + (size_t)(t0+t)*DM + d;
      float a = a0 + p[0]*cr.w;
      if (tl >= 1) a += p[-DM]*cr.z;
      if (tl >= 2) a += p[-2*DM]*cr.y;
      if (tl >= 3) a += p[-3*DM]*cr.x;
      xs[t*DM + d] = silu(a);
    }
  }
  __syncthreads();

  int n = tid & 63, grp = tid >> 6;
  const float* wr = xpw + (size_t)n*DM;
  float a[4] = {0.f,0.f,0.f,0.f};
  for (int k=0;k<DM;k+=4){
    float4 w4 = *(const float4*)(wr + k);
    #pragma unroll
    for (int q=0;q<4;q++){
      float4 xv = *(const float4*)&xs[(grp*4+q)*DM + k];
      a[q] += xv.x*w4.x + xv.y*w4.y + xv.z*w4.z + xv.w*w4.w;
    }
  }
  #pragma unroll
  for (int q=0;q<4;q++) pj[(grp*4+q)*64 + n] = a[q];
  __syncthreads();

  for (int i=tid; i<16*32; i+=256){
    int tt = i >> 5, c = i & 31;
    float v = pj[tt*64 + 32 + c];
    if (c < 16) Bc[(size_t)(t0+tt)*16 + c]      = v;
    else        Cc[(size_t)(t0+tt)*16 + (c-16)] = v;
  }

  #pragma unroll
  for (int jn=0;jn<2;jn++){
    int nn = tid + 256*jn;
    const float* dr = dtw + (size_t)nn*32;
    float wv[32];
    #pragma unroll
    for (int r=0;r<32;r+=4){
      float4 t4 = *(const float4*)(dr + r);
      wv[r]=t4.x; wv[r+1]=t4.y; wv[r+2]=t4.z; wv[r+3]=t4.w;
    }
    float bb = dtb[nn];
    for (int tt=0;tt<16;tt++){
      const float* pr = &pj[tt*64];
      float s = bb;
      #pragma unroll
      for (int r=0;r<32;r++) s += pr[r]*wv[r];
      float sp = (s > 20.f) ? s : log1pf(__expf(s));
      dt[(size_t)(t0+tt)*DM + nn] = sp;
    }
  }
}

// ------ K4: selective scan (conv on the fly) -> ya = bf16((y+xc*D)*zs) ------
__global__ __launch_bounds__(64) void k_scan(const float* __restrict__ dt,
                                             const float* __restrict__ xi,
                                             const unsigned short* __restrict__ zs,
                                             const float* __restrict__ Bc,
                                             const float* __restrict__ Cc,
                                             const float* __restrict__ cw,
                                             const float* __restrict__ cb,
                                             const float* __restrict__ Alog,
                                             const float* __restrict__ Dpw,
                                             unsigned short* __restrict__ ya){
  int gid = blockIdx.x*64 + threadIdx.x;   // (b,d)
  int d = gid & 511;
  int b = gid >> 9;
  float A[16];
  #pragma unroll
  for (int s=0;s<16;s++) A[s] = -__expf(Alog[d*16 + s]);
  float Dv = Dpw[d];
  float4 cr = *(const float4*)(cw + d*4);
  float cbv = cb[d];
  float h[16];
  #pragma unroll
  for (int s=0;s<16;s++) h[s] = 0.f;
  float xm1=0.f, xm2=0.f, xm3=0.f;
  size_t base = (size_t)b*256*DM + d;
  const float* dtp = dt + base;
  const float* xip = xi + base;
  const unsigned short* zsp = zs + base;
  unsigned short* yap = ya + base;
  const float* Bp = Bc + (size_t)b*256*16;
  const float* Cp = Cc + (size_t)b*256*16;
  for (int t=0;t<256;t++){
    float xt = xip[t*DM];
    float a  = cbv + xm3*cr.x + xm2*cr.y + xm1*cr.z + xt*cr.w;
    float u  = silu(a);
    float dv = dtp[t*DM];
    float du = dv*u;
    float y  = 0.f;
    #pragma unroll
    for (int s=0;s<16;s++){
      float dA = __expf(dv*A[s]);
      h[s] = dA*h[s] + du*Bp[t*16+s];
      y   += h[s]*Cp[t*16+s];
    }
    yap[t*DM] = f2bf((y + u*Dv) * bfu(zsp[t*DM]));
    xm3 = xm2; xm2 = xm1; xm1 = xt;
  }
}

// ---------------- K5: out = LayerNorm(o + slots) (f32) ----------------------
__global__ __launch_bounds__(64) void k_fln(const float* __restrict__ o,
                                            const float* __restrict__ resid,
                                            const float* __restrict__ g,
                                            const float* __restrict__ b,
                                            float* __restrict__ out){
  int tok  = blockIdx.x;
  int lane = threadIdx.x;
  const float* row = o     + (size_t)tok*DM + lane*8;
  const float* rr  = resid + (size_t)tok*DM + lane*8;
  float4 r0 = *(const float4*)row;
  float4 r1 = *(const float4*)(row + 4);
  float4 s0 = *(const float4*)rr;
  float4 s1 = *(const float4*)(rr + 4);
  float v[8] = {r0.x+s0.x, r0.y+s0.y, r0.z+s0.z, r0.w+s0.w,
                r1.x+s1.x, r1.y+s1.y, r1.z+s1.z, r1.w+s1.w};
  float s = 0.f;
  #pragma unroll
  for (int i=0;i<8;i++) s += v[i];
  #pragma unroll
  for (int o2=32;o2;o2>>=1) s += __shfl_xor(s, o2, 64);
  float m = s * (1.0f/512.0f);
  float vs = 0.f;
  #pragma unroll
  for (int i=0;i<8;i++){ float d = v[i]-m; vs += d*d; }
  #pragma unroll
  for (int o2=32;o2;o2>>=1) vs += __shfl_xor(vs, o2, 64);
  float rs = rsqrtf(vs*(1.0f/512.0f) + 1e-5f);
  float4 g0 = *(const float4*)(g + lane*8);
  float4 g1 = *(const float4*)(g + lane*8 + 4);
  float4 b0 = *(const float4*)(b + lane*8);
  float4 b1 = *(const float4*)(b + lane*8 + 4);
  float gv[8] = {g0.x,g0.y,g0.z,g0.w, g1.x,g1.y,g1.z,g1.w};
  float bv[8] = {b0.x,b0.y,b0.z,b0.w, b1.x,b1.y,b1.z,b1.w};
  float o8[8];
  #pragma unroll
  for (int i=0;i<8;i++) o8[i] = (v[i]-m)*rs*gv[i] + bv[i];
  float4* op = (float4*)(out + (size_t)tok*DM + lane*8);
  op[0] = make_float4(o8[0],o8[1],o8[2],o8[3]);
  op[1] = make_float4(o8[4],o8[5],o8[6],o8[7]);
}

extern "C" void kernel_launch(void* const* d_in, const int* in_sizes, int n_in,
                              void* d_out, int out_size, void* d_ws, size_t ws_size,
                              hipStream_t stream) {
  const float* slots     = (const float*)d_in[0];
  const float* ln_g      = (const float*)d_in[1];
  const float* ln_b      = (const float*)d_in[2];
  const float* in_proj_w = (const float*)d_in[3];
  const float* conv_w    = (const float*)d_in[4];
  const float* conv_b    = (const float*)d_in[5];
  const float* x_proj_w  = (const float*)d_in[6];
  const float* dt_proj_w = (const float*)d_in[7];
  const float* dt_proj_b = (const float*)d_in[8];
  const float* A_log     = (const float*)d_in[9];
  const float* Dp        = (const float*)d_in[10];
  const float* out_projw = (const float*)d_in[11];
  const float* fln_g     = (const float*)d_in[12];
  const float* fln_b     = (const float*)d_in[13];
  float* out = (float*)d_out;

  const size_t MB = 1024*1024;
  char* base = (char*)d_ws;
  float*          xi   = (float*)(base);                    // [0,32MB)
  unsigned short* xlnb = (unsigned short*)(base + 32*MB);   // [32,48MB); reused as yab
  unsigned short* yab  = xlnb;
  unsigned short* zsb  = (unsigned short*)(base + 48*MB);   // [48,64MB)
  float*          dto  = (float*)(base + 64*MB);            // [64,96MB): dt, then o
  float*          Bc   = (float*)(base + 96*MB);
  float*          Cc   = (float*)(base + 97*MB);

  k_ln   <<<NTOK,           64, 0, stream>>>(slots, ln_g, ln_b, xlnb);
  k_gemm <<<dim3(512, 8),  256, 0, stream>>>(xlnb, in_proj_w, xi, zsb, 0);
  k_xproj<<<NTOK/16,       256, 0, stream>>>(xi, conv_w, conv_b, x_proj_w, dt_proj_w, dt_proj_b,
                                             dto, Bc, Cc);
  k_scan <<<512,            64, 0, stream>>>(dto, xi, zsb, Bc, Cc, conv_w, conv_b, A_log, Dp, yab);
  k_gemm <<<dim3(512, 4),  256, 0, stream>>>(yab, out_projw, dto, zsb, 1);
  k_fln  <<<NTOK,           64, 0, stream>>>(dto, slots, fln_g, fln_b, out);
}

// Round 6
// 561.831 us; speedup vs baseline: 2.3691x; 1.1592x over previous
//
#include <hip/hip_runtime.h>
#include <hip/hip_bf16.h>

// SlotMamba: B=64, K=256, D_MODEL=512, D_INNER=512, D_STATE=16, D_CONV=4, DT_RANK=32
// NTOK = 16384 tokens. Inputs f32, output f32.
// GEMMs (in_proj 16384x1024x512, out_proj 16384x512x512) run as bf16 MFMA
// (16x16x32) with f32 accumulation; everything else stays f32.
//
// ws layout (bytes, MB = 2^20):       lifetime
//   xi    [0,  32MB) f32              k_gemm(in) -> k_xproj, k_scan
//   xlnb  [32, 48MB) bf16 (A of in)   k_ln -> k_gemm(in);  reused as yab: k_scan -> k_gemm(out)
//   zsb   [48, 64MB) bf16             k_gemm(in) -> k_scan
//   dt/o  [64, 96MB) f32              k_xproj -> k_scan;   reused as o: k_gemm(out) -> k_fln
//   Bc    [96, 97MB), Cc [97, 98MB)   k_xproj -> k_scan
// total 98 MiB.

#define NTOK 16384
#define DM   512

typedef __attribute__((ext_vector_type(8))) short bf16x8;   // 8 bf16 = 4 VGPRs
typedef __attribute__((ext_vector_type(4))) float f32x4;

__device__ __forceinline__ unsigned short f2bf(float f){
  unsigned int u = __float_as_uint(f);
  u = (u + 0x7fffu + ((u >> 16) & 1u)) >> 16;   // RNE
  return (unsigned short)u;
}
__device__ __forceinline__ float bfu(unsigned short p){ return __uint_as_float(((unsigned int)p) << 16); }
__device__ __forceinline__ unsigned int pk2(float a, float b){
  return (unsigned int)f2bf(a) | ((unsigned int)f2bf(b) << 16);
}
__device__ __forceinline__ float silu(float a){ return a / (1.f + __expf(-a)); }

// ---------------- K1: LayerNorm(slots) -> xlnb (bf16) -----------------------
__global__ __launch_bounds__(64) void k_ln(const float* __restrict__ x,
                                           const float* __restrict__ g,
                                           const float* __restrict__ b,
                                           unsigned short* __restrict__ out){
  int tok  = blockIdx.x;
  int lane = threadIdx.x;
  const float* row = x + (size_t)tok*DM + lane*8;
  float4 r0 = *(const float4*)row;
  float4 r1 = *(const float4*)(row + 4);
  float v[8] = {r0.x,r0.y,r0.z,r0.w, r1.x,r1.y,r1.z,r1.w};
  float s = 0.f;
  #pragma unroll
  for (int i=0;i<8;i++) s += v[i];
  #pragma unroll
  for (int o=32;o;o>>=1) s += __shfl_xor(s, o, 64);
  float m = s * (1.0f/512.0f);
  float vs = 0.f;
  #pragma unroll
  for (int i=0;i<8;i++){ float d = v[i]-m; vs += d*d; }
  #pragma unroll
  for (int o=32;o;o>>=1) vs += __shfl_xor(vs, o, 64);
  float rs = rsqrtf(vs*(1.0f/512.0f) + 1e-5f);
  float4 g0 = *(const float4*)(g + lane*8);
  float4 g1 = *(const float4*)(g + lane*8 + 4);
  float4 b0 = *(const float4*)(b + lane*8);
  float4 b1 = *(const float4*)(b + lane*8 + 4);
  float gv[8] = {g0.x,g0.y,g0.z,g0.w, g1.x,g1.y,g1.z,g1.w};
  float bv[8] = {b0.x,b0.y,b0.z,b0.w, b1.x,b1.y,b1.z,b1.w};
  float o8[8];
  #pragma unroll
  for (int i=0;i<8;i++) o8[i] = (v[i]-m)*rs*gv[i] + bv[i];
  uint4 st = { pk2(o8[0],o8[1]), pk2(o8[2],o8[3]), pk2(o8[4],o8[5]), pk2(o8[6],o8[7]) };
  *(uint4*)(out + (size_t)tok*DM + lane*8) = st;
}

// ---------------- K2: generic bf16-MFMA GEMM  C = A @ W^T -------------------
__global__ __launch_bounds__(256) void k_gemm(const unsigned short* __restrict__ A,
                                              const float* __restrict__ W,
                                              float* __restrict__ out_f,
                                              unsigned short* __restrict__ out_b,
                                              int mode){
  __shared__ unsigned short As[32*520];   // +8 pad: conflict-free frag reads
  __shared__ unsigned short Bs[128*40];   // per-K-step 128 x 32, +8 pad
  int t0  = blockIdx.x * 32;
  int n0  = blockIdx.y * 128;
  int tid = threadIdx.x;
  int lane = tid & 63;
  int wv  = tid >> 6;
  int mw  = wv >> 1, nw = wv & 1;

  for (int i = tid; i < 32*64; i += 256){
    int r = i >> 6, c = (i & 63) * 8;
    *(uint4*)&As[r*520 + c] = *(const uint4*)(A + (size_t)(t0+r)*DM + c);
  }

  f32x4 acc[4];
  #pragma unroll
  for (int j=0;j<4;j++) acc[j] = (f32x4){0.f,0.f,0.f,0.f};

  int n = tid >> 1, half = (tid & 1) * 16;
  const float* wp = W + (size_t)(n0 + n)*DM + half;
  int m15 = lane & 15, quad = lane >> 4;

  for (int ks = 0; ks < 16; ks++){
    int k0 = ks * 32;
    float4 w0 = *(const float4*)(wp + k0);
    float4 w1 = *(const float4*)(wp + k0 + 4);
    float4 w2 = *(const float4*)(wp + k0 + 8);
    float4 w3 = *(const float4*)(wp + k0 + 12);
    __syncthreads();
    uint4 lo = { pk2(w0.x,w0.y), pk2(w0.z,w0.w), pk2(w1.x,w1.y), pk2(w1.z,w1.w) };
    uint4 hi = { pk2(w2.x,w2.y), pk2(w2.z,w2.w), pk2(w3.x,w3.y), pk2(w3.z,w3.w) };
    *(uint4*)&Bs[n*40 + half]     = lo;
    *(uint4*)&Bs[n*40 + half + 8] = hi;
    __syncthreads();
    bf16x8 af = *(const bf16x8*)&As[(mw*16 + m15)*520 + k0 + quad*8];
    #pragma unroll
    for (int j=0;j<4;j++){
      bf16x8 bfr = *(const bf16x8*)&Bs[(nw*64 + j*16 + m15)*40 + quad*8];
      acc[j] = __builtin_amdgcn_mfma_f32_16x16x32_bf16(af, bfr, acc[j], 0, 0, 0);
    }
  }

  #pragma unroll
  for (int j=0;j<4;j++){
    int nn = n0 + nw*64 + j*16 + m15;
    #pragma unroll
    for (int r=0;r<4;r++){
      int tok = t0 + mw*16 + quad*4 + r;
      float v = acc[j][r];
      if (mode == 0){
        if (nn < DM) out_f[(size_t)tok*DM + nn] = v;
        else         out_b[(size_t)tok*DM + (nn - DM)] = f2bf(silu(v));
      } else {
        out_f[(size_t)tok*DM + nn] = v;
      }
    }
  }
}

// -------- K3: conv4+silu (on the fly) ; proj = xc @ x_proj_w.T ; dt ---------
__global__ __launch_bounds__(256) void k_xproj(const float* __restrict__ xi,
                                               const float* __restrict__ cw,
                                               const float* __restrict__ cb,
                                               const float* __restrict__ xpw,
                                               const float* __restrict__ dtw,
                                               const float* __restrict__ dtb,
                                               float* __restrict__ dt,
                                               float* __restrict__ Bc,
                                               float* __restrict__ Cc){
  __shared__ __align__(16) float xs[16*DM];
  __shared__ __align__(16) float pj[16*64];
  int t0  = blockIdx.x * 16;
  int tid = threadIdx.x;

  #pragma unroll
  for (int j=0;j<2;j++){
    int d = tid + 256*j;
    float4 cr = *(const float4*)(cw + d*4);
    float a0 = cb[d];
    for (int t=0;t<16;t++){
      int tl = (t0 + t) & 255;
      const float* p = xi + (size_t)(t0+t)*DM + d;
      float a = a0 + p[0]*cr.w;
      if (tl >= 1) a += p[-DM]*cr.z;
      if (tl >= 2) a += p[-2*DM]*cr.y;
      if (tl >= 3) a += p[-3*DM]*cr.x;
      xs[t*DM + d] = silu(a);
    }
  }
  __syncthreads();

  int n = tid & 63, grp = tid >> 6;
  const float* wr = xpw + (size_t)n*DM;
  float a[4] = {0.f,0.f,0.f,0.f};
  for (int k=0;k<DM;k+=4){
    float4 w4 = *(const float4*)(wr + k);
    #pragma unroll
    for (int q=0;q<4;q++){
      float4 xv = *(const float4*)&xs[(grp*4+q)*DM + k];
      a[q] += xv.x*w4.x + xv.y*w4.y + xv.z*w4.z + xv.w*w4.w;
    }
  }
  #pragma unroll
  for (int q=0;q<4;q++) pj[(grp*4+q)*64 + n] = a[q];
  __syncthreads();

  for (int i=tid; i<16*32; i+=256){
    int tt = i >> 5, c = i & 31;
    float v = pj[tt*64 + 32 + c];
    if (c < 16) Bc[(size_t)(t0+tt)*16 + c]      = v;
    else        Cc[(size_t)(t0+tt)*16 + (c-16)] = v;
  }

  #pragma unroll
  for (int jn=0;jn<2;jn++){
    int nn = tid + 256*jn;
    const float* dr = dtw + (size_t)nn*32;
    float wv[32];
    #pragma unroll
    for (int r=0;r<32;r+=4){
      float4 t4 = *(const float4*)(dr + r);
      wv[r]=t4.x; wv[r+1]=t4.y; wv[r+2]=t4.z; wv[r+3]=t4.w;
    }
    float bb = dtb[nn];
    for (int tt=0;tt<16;tt++){
      const float* pr = &pj[tt*64];
      float s = bb;
      #pragma unroll
      for (int r=0;r<32;r++) s += pr[r]*wv[r];
      float sp = (s > 20.f) ? s : log1pf(__expf(s));
      dt[(size_t)(t0+tt)*DM + nn] = sp;
    }
  }
}

// ------ K4: selective scan, state-parallel: 4 lanes x 4 states per (b,d) ----
// 131072 threads = 2048 waves = 8 waves/CU (vs 512 waves before).
__global__ __launch_bounds__(256) void k_scan(const float* __restrict__ dt,
                                              const float* __restrict__ xi,
                                              const unsigned short* __restrict__ zs,
                                              const float* __restrict__ Bc,
                                              const float* __restrict__ Cc,
                                              const float* __restrict__ cw,
                                              const float* __restrict__ cb,
                                              const float* __restrict__ Alog,
                                              const float* __restrict__ Dpw,
                                              unsigned short* __restrict__ ya){
  int tid = threadIdx.x;
  int sl  = tid & 3;                       // state slice: states sl*4..sl*4+3
  int q   = blockIdx.x*64 + (tid >> 2);    // (b,d) pair; block covers 64 consecutive d
  int d   = q & 511;
  int b   = q >> 9;
  float4 Alr = *(const float4*)(Alog + d*16 + sl*4);
  float A0 = -__expf(Alr.x), A1 = -__expf(Alr.y);
  float A2 = -__expf(Alr.z), A3 = -__expf(Alr.w);
  float Dv = Dpw[d];
  float4 cr = *(const float4*)(cw + d*4);
  float cbv = cb[d];
  float h0=0.f, h1=0.f, h2=0.f, h3=0.f;
  float xm1=0.f, xm2=0.f, xm3=0.f;
  size_t base = (size_t)b*256*DM + d;
  const float* dtp = dt + base;
  const float* xip = xi + base;
  const unsigned short* zsp = zs + base;
  unsigned short* yap = ya + base;
  const float* Bp = Bc + (size_t)b*256*16 + sl*4;
  const float* Cp = Cc + (size_t)b*256*16 + sl*4;
  #pragma unroll 4
  for (int t=0;t<256;t++){
    float xt  = xip[(size_t)t*DM];
    float dv  = dtp[(size_t)t*DM];
    float4 Bv = *(const float4*)(Bp + t*16);
    float4 Cv = *(const float4*)(Cp + t*16);
    float a  = cbv + xm3*cr.x + xm2*cr.y + xm1*cr.z + xt*cr.w;
    float u  = silu(a);
    float du = dv*u;
    h0 = __expf(dv*A0)*h0 + du*Bv.x;
    h1 = __expf(dv*A1)*h1 + du*Bv.y;
    h2 = __expf(dv*A2)*h2 + du*Bv.z;
    h3 = __expf(dv*A3)*h3 + du*Bv.w;
    float yy = h0*Cv.x + h1*Cv.y + h2*Cv.z + h3*Cv.w;
    yy += __shfl_xor(yy, 1);
    yy += __shfl_xor(yy, 2);
    if (sl == 0) yap[(size_t)t*DM] = f2bf((yy + u*Dv) * bfu(zsp[(size_t)t*DM]));
    xm3 = xm2; xm2 = xm1; xm1 = xt;
  }
}

// ---------------- K5: out = LayerNorm(o + slots) (f32) ----------------------
__global__ __launch_bounds__(64) void k_fln(const float* __restrict__ o,
                                            const float* __restrict__ resid,
                                            const float* __restrict__ g,
                                            const float* __restrict__ b,
                                            float* __restrict__ out){
  int tok  = blockIdx.x;
  int lane = threadIdx.x;
  const float* row = o     + (size_t)tok*DM + lane*8;
  const float* rr  = resid + (size_t)tok*DM + lane*8;
  float4 r0 = *(const float4*)row;
  float4 r1 = *(const float4*)(row + 4);
  float4 s0 = *(const float4*)rr;
  float4 s1 = *(const float4*)(rr + 4);
  float v[8] = {r0.x+s0.x, r0.y+s0.y, r0.z+s0.z, r0.w+s0.w,
                r1.x+s1.x, r1.y+s1.y, r1.z+s1.z, r1.w+s1.w};
  float s = 0.f;
  #pragma unroll
  for (int i=0;i<8;i++) s += v[i];
  #pragma unroll
  for (int o2=32;o2;o2>>=1) s += __shfl_xor(s, o2, 64);
  float m = s * (1.0f/512.0f);
  float vs = 0.f;
  #pragma unroll
  for (int i=0;i<8;i++){ float d = v[i]-m; vs += d*d; }
  #pragma unroll
  for (int o2=32;o2;o2>>=1) vs += __shfl_xor(vs, o2, 64);
  float rs = rsqrtf(vs*(1.0f/512.0f) + 1e-5f);
  float4 g0 = *(const float4*)(g + lane*8);
  float4 g1 = *(const float4*)(g + lane*8 + 4);
  float4 b0 = *(const float4*)(b + lane*8);
  float4 b1 = *(const float4*)(b + lane*8 + 4);
  float gv[8] = {g0.x,g0.y,g0.z,g0.w, g1.x,g1.y,g1.z,g1.w};
  float bv[8] = {b0.x,b0.y,b0.z,b0.w, b1.x,b1.y,b1.z,b1.w};
  float o8[8];
  #pragma unroll
  for (int i=0;i<8;i++) o8[i] = (v[i]-m)*rs*gv[i] + bv[i];
  float4* op = (float4*)(out + (size_t)tok*DM + lane*8);
  op[0] = make_float4(o8[0],o8[1],o8[2],o8[3]);
  op[1] = make_float4(o8[4],o8[5],o8[6],o8[7]);
}

extern "C" void kernel_launch(void* const* d_in, const int* in_sizes, int n_in,
                              void* d_out, int out_size, void* d_ws, size_t ws_size,
                              hipStream_t stream) {
  const float* slots     = (const float*)d_in[0];
  const float* ln_g      = (const float*)d_in[1];
  const float* ln_b      = (const float*)d_in[2];
  const float* in_proj_w = (const float*)d_in[3];
  const float* conv_w    = (const float*)d_in[4];
  const float* conv_b    = (const float*)d_in[5];
  const float* x_proj_w  = (const float*)d_in[6];
  const float* dt_proj_w = (const float*)d_in[7];
  const float* dt_proj_b = (const float*)d_in[8];
  const float* A_log     = (const float*)d_in[9];
  const float* Dp        = (const float*)d_in[10];
  const float* out_projw = (const float*)d_in[11];
  const float* fln_g     = (const float*)d_in[12];
  const float* fln_b     = (const float*)d_in[13];
  float* out = (float*)d_out;

  const size_t MB = 1024*1024;
  char* base = (char*)d_ws;
  float*          xi   = (float*)(base);                    // [0,32MB)
  unsigned short* xlnb = (unsigned short*)(base + 32*MB);   // [32,48MB); reused as yab
  unsigned short* yab  = xlnb;
  unsigned short* zsb  = (unsigned short*)(base + 48*MB);   // [48,64MB)
  float*          dto  = (float*)(base + 64*MB);            // [64,96MB): dt, then o
  float*          Bc   = (float*)(base + 96*MB);
  float*          Cc   = (float*)(base + 97*MB);

  k_ln   <<<NTOK,           64, 0, stream>>>(slots, ln_g, ln_b, xlnb);
  k_gemm <<<dim3(512, 8),  256, 0, stream>>>(xlnb, in_proj_w, xi, zsb, 0);
  k_xproj<<<NTOK/16,       256, 0, stream>>>(xi, conv_w, conv_b, x_proj_w, dt_proj_w, dt_proj_b,
                                             dto, Bc, Cc);
  k_scan <<<512,           256, 0, stream>>>(dto, xi, zsb, Bc, Cc, conv_w, conv_b, A_log, Dp, yab);
  k_gemm <<<dim3(512, 4),  256, 0, stream>>>(yab, out_projw, dto, zsb, 1);
  k_fln  <<<NTOK,           64, 0, stream>>>(dto, slots, fln_g, fln_b, out);
}

// Round 7
// 515.854 us; speedup vs baseline: 2.5802x; 1.0891x over previous
//
#include <hip/hip_runtime.h>
#include <hip/hip_bf16.h>

// SlotMamba: B=64, K=256, D_MODEL=512, D_INNER=512, D_STATE=16, D_CONV=4, DT_RANK=32
// NTOK = 16384. Inputs f32, output f32. GEMMs: bf16 MFMA 16x16x32, f32 accum.
// dt/xi/zs use T-layout (time-major): index [(b*512+d)*256 + t] -> contiguous
// per-(b,d) streams for the scan.
//
// ws layout (MB = 2^20):                lifetime
//   xiT  [0,  32MB) f32 T-layout        gemm(in) -> xproj, scan
//   xlnb [32, 48MB) bf16 [t][d]         ln -> gemm(in); reused as yab: scan -> gemm(out)
//   zsT  [48, 64MB) bf16 T-layout       gemm(in) -> scan; first 1MB reused as WbO after scan
//   dtT/o[64, 96MB) f32                 first 1MB = WbI (cvtw -> gemm(in)); then dtT: xproj -> scan;
//                                       then o [t][d]: gemm(out) -> fln
//   Bc   [96, 97MB), Cc [97, 98MB)      xproj -> scan
// total 98 MiB.

#define NTOK 16384
#define DM   512

typedef __attribute__((ext_vector_type(8))) short bf16x8;
typedef __attribute__((ext_vector_type(4))) float f32x4;

__device__ __forceinline__ unsigned short f2bf(float f){
  unsigned int u = __float_as_uint(f);
  u = (u + 0x7fffu + ((u >> 16) & 1u)) >> 16;   // RNE
  return (unsigned short)u;
}
__device__ __forceinline__ float bfu(unsigned short p){ return __uint_as_float(((unsigned int)p) << 16); }
__device__ __forceinline__ unsigned int pk2(float a, float b){
  return (unsigned int)f2bf(a) | ((unsigned int)f2bf(b) << 16);
}
__device__ __forceinline__ float silu(float a){ return a / (1.f + __expf(-a)); }

// ---------------- K0: f32 -> bf16 weight convert ----------------------------
__global__ __launch_bounds__(256) void k_cvtw(const float* __restrict__ W,
                                              unsigned short* __restrict__ Wb){
  int i = (blockIdx.x*256 + threadIdx.x)*8;
  float4 a = *(const float4*)(W+i);
  float4 b = *(const float4*)(W+i+4);
  uint4 st = { pk2(a.x,a.y), pk2(a.z,a.w), pk2(b.x,b.y), pk2(b.z,b.w) };
  *(uint4*)(Wb+i) = st;
}

// ---------------- K1: LayerNorm(slots) -> xlnb (bf16, [t][d]) ---------------
__global__ __launch_bounds__(64) void k_ln(const float* __restrict__ x,
                                           const float* __restrict__ g,
                                           const float* __restrict__ b,
                                           unsigned short* __restrict__ out){
  int tok  = blockIdx.x;
  int lane = threadIdx.x;
  const float* row = x + (size_t)tok*DM + lane*8;
  float4 r0 = *(const float4*)row;
  float4 r1 = *(const float4*)(row + 4);
  float v[8] = {r0.x,r0.y,r0.z,r0.w, r1.x,r1.y,r1.z,r1.w};
  float s = 0.f;
  #pragma unroll
  for (int i=0;i<8;i++) s += v[i];
  #pragma unroll
  for (int o=32;o;o>>=1) s += __shfl_xor(s, o, 64);
  float m = s * (1.0f/512.0f);
  float vs = 0.f;
  #pragma unroll
  for (int i=0;i<8;i++){ float d = v[i]-m; vs += d*d; }
  #pragma unroll
  for (int o=32;o;o>>=1) vs += __shfl_xor(vs, o, 64);
  float rs = rsqrtf(vs*(1.0f/512.0f) + 1e-5f);
  float4 g0 = *(const float4*)(g + lane*8);
  float4 g1 = *(const float4*)(g + lane*8 + 4);
  float4 b0 = *(const float4*)(b + lane*8);
  float4 b1 = *(const float4*)(b + lane*8 + 4);
  float gv[8] = {g0.x,g0.y,g0.z,g0.w, g1.x,g1.y,g1.z,g1.w};
  float bv[8] = {b0.x,b0.y,b0.z,b0.w, b1.x,b1.y,b1.z,b1.w};
  float o8[8];
  #pragma unroll
  for (int i=0;i<8;i++) o8[i] = (v[i]-m)*rs*gv[i] + bv[i];
  uint4 st = { pk2(o8[0],o8[1]), pk2(o8[2],o8[3]), pk2(o8[4],o8[5]), pk2(o8[6],o8[7]) };
  *(uint4*)(out + (size_t)tok*DM + lane*8) = st;
}

// ---------------- K2: bf16-MFMA GEMM  C = A @ Wb^T --------------------------
// A: [NTOK][512] bf16. Wb: [N][512] bf16 (preconverted). No B-staging: B-frags
// loaded straight from L1/L2-hot Wb. One barrier total (A-tile stage).
// mode 0 (in_proj): nn<512 -> xiT f32 (T-layout); nn>=512 -> zsT bf16 silu.
// mode 1 (out_proj): o [t][d] f32.
__global__ __launch_bounds__(256) void k_gemm(const unsigned short* __restrict__ A,
                                              const unsigned short* __restrict__ Wb,
                                              float* __restrict__ out_f,
                                              unsigned short* __restrict__ out_b,
                                              int mode){
  __shared__ unsigned short As[32*520];
  int t0  = blockIdx.x * 32;
  int n0  = blockIdx.y * 128;
  int tid = threadIdx.x;
  int lane = tid & 63;
  int wv  = tid >> 6;
  int mw  = wv >> 1, nw = wv & 1;
  int m15 = lane & 15, quad = lane >> 4;

  for (int i = tid; i < 32*64; i += 256){
    int r = i >> 6, c = (i & 63) * 8;
    *(uint4*)&As[r*520 + c] = *(const uint4*)(A + (size_t)(t0+r)*DM + c);
  }
  __syncthreads();

  f32x4 acc[4];
  #pragma unroll
  for (int j=0;j<4;j++) acc[j] = (f32x4){0.f,0.f,0.f,0.f};

  const unsigned short* wbase = Wb + (size_t)(n0 + nw*64 + m15)*DM + quad*8;
  #pragma unroll 4
  for (int ks = 0; ks < 16; ks++){
    int k0 = ks * 32;
    bf16x8 af = *(const bf16x8*)&As[(mw*16 + m15)*520 + k0 + quad*8];
    #pragma unroll
    for (int j=0;j<4;j++){
      bf16x8 bfr = *(const bf16x8*)(wbase + (size_t)j*16*DM + k0);
      acc[j] = __builtin_amdgcn_mfma_f32_16x16x32_bf16(af, bfr, acc[j], 0, 0, 0);
    }
  }

  int tok0 = t0 + mw*16 + quad*4;          // 4 consecutive tokens: tok0..tok0+3
  int b    = tok0 >> 8;
  int tl0  = tok0 & 255;                   // multiple of 4 -> 16B-aligned T-stores
  #pragma unroll
  for (int j=0;j<4;j++){
    int nn = n0 + nw*64 + j*16 + m15;
    if (mode == 0){
      if (nn < DM){
        *(f32x4*)(out_f + ((size_t)(b*DM + nn))*256 + tl0) = acc[j];
      } else {
        uint2 z2 = { pk2(silu(acc[j][0]), silu(acc[j][1])),
                     pk2(silu(acc[j][2]), silu(acc[j][3])) };
        *(uint2*)(out_b + ((size_t)(b*DM + (nn-DM)))*256 + tl0) = z2;
      }
    } else {
      #pragma unroll
      for (int r=0;r<4;r++) out_f[(size_t)(tok0+r)*DM + nn] = acc[j][r];
    }
  }
}

// -------- K3: conv4+silu (T-layout reads) ; proj ; dt -> dtT ----------------
__global__ __launch_bounds__(256) void k_xproj(const float* __restrict__ xiT,
                                               const float* __restrict__ cw,
                                               const float* __restrict__ cb,
                                               const float* __restrict__ xpw,
                                               const float* __restrict__ dtw,
                                               const float* __restrict__ dtb,
                                               float* __restrict__ dtT,
                                               float* __restrict__ Bc,
                                               float* __restrict__ Cc){
  __shared__ __align__(16) float xs[16*DM];
  __shared__ __align__(16) float pj[16*64];
  int t0  = blockIdx.x * 16;               // 16 tokens, all within one sequence b
  int b   = t0 >> 8;
  int tl0 = t0 & 255;
  int tid = threadIdx.x;

  // conv4 + silu: thread d reads its contiguous T-stream window
  #pragma unroll
  for (int j=0;j<2;j++){
    int d = tid + 256*j;
    float4 cr = *(const float4*)(cw + d*4);
    float a0 = cb[d];
    const float* row = xiT + ((size_t)(b*DM + d))*256;
    float w[20];                           // w[i] = x at time tl0-4+i
    if (tl0 == 0){
      w[0]=w[1]=w[2]=w[3]=0.f;
      #pragma unroll
      for (int q=0;q<4;q++){
        float4 v4 = *(const float4*)(row + q*4);
        w[4+q*4]=v4.x; w[5+q*4]=v4.y; w[6+q*4]=v4.z; w[7+q*4]=v4.w;
      }
    } else {
      const float* p4 = row + tl0 - 4;     // (tl0-4)%16==12 -> 48B offset, 16B-aligned
      #pragma unroll
      for (int q=0;q<5;q++){
        float4 v4 = *(const float4*)(p4 + q*4);
        w[q*4]=v4.x; w[1+q*4]=v4.y; w[2+q*4]=v4.z; w[3+q*4]=v4.w;
      }
    }
    #pragma unroll
    for (int t=0;t<16;t++){
      float a = a0 + w[t+1]*cr.x + w[t+2]*cr.y + w[t+3]*cr.z + w[t+4]*cr.w;
      xs[t*DM + d] = silu(a);
    }
  }
  __syncthreads();

  int n = tid & 63, grp = tid >> 6;
  const float* wr = xpw + (size_t)n*DM;
  float a[4] = {0.f,0.f,0.f,0.f};
  for (int k=0;k<DM;k+=4){
    float4 w4 = *(const float4*)(wr + k);
    #pragma unroll
    for (int q=0;q<4;q++){
      float4 xv = *(const float4*)&xs[(grp*4+q)*DM + k];
      a[q] += xv.x*w4.x + xv.y*w4.y + xv.z*w4.z + xv.w*w4.w;
    }
  }
  #pragma unroll
  for (int q=0;q<4;q++) pj[(grp*4+q)*64 + n] = a[q];
  __syncthreads();

  for (int i=tid; i<16*32; i+=256){
    int tt = i >> 5, c = i & 31;
    float v = pj[tt*64 + 32 + c];
    if (c < 16) Bc[(size_t)(t0+tt)*16 + c]      = v;
    else        Cc[(size_t)(t0+tt)*16 + (c-16)] = v;
  }

  #pragma unroll
  for (int jn=0;jn<2;jn++){
    int nn = tid + 256*jn;
    const float* dr = dtw + (size_t)nn*32;
    float wv[32];
    #pragma unroll
    for (int r=0;r<32;r+=4){
      float4 t4 = *(const float4*)(dr + r);
      wv[r]=t4.x; wv[r+1]=t4.y; wv[r+2]=t4.z; wv[r+3]=t4.w;
    }
    float bb = dtb[nn];
    float dts[16];
    #pragma unroll
    for (int tt=0;tt<16;tt++){
      const float* pr = &pj[tt*64];
      float s = bb;
      #pragma unroll
      for (int r=0;r<32;r++) s += pr[r]*wv[r];
      dts[tt] = (s > 20.f) ? s : log1pf(__expf(s));
    }
    float* dst = dtT + ((size_t)(b*DM + nn))*256 + tl0;
    #pragma unroll
    for (int q=0;q<4;q++)
      *(float4*)(dst + q*4) = make_float4(dts[q*4],dts[q*4+1],dts[q*4+2],dts[q*4+3]);
  }
}

// ------ K4: scan, 4 lanes x 4 states per (b,d); T-layout float4 streams -----
__global__ __launch_bounds__(256) void k_scan(const float* __restrict__ dtT,
                                              const float* __restrict__ xiT,
                                              const unsigned short* __restrict__ zsT,
                                              const float* __restrict__ Bc,
                                              const float* __restrict__ Cc,
                                              const float* __restrict__ cw,
                                              const float* __restrict__ cb,
                                              const float* __restrict__ Alog,
                                              const float* __restrict__ Dpw,
                                              unsigned short* __restrict__ ya){
  int tid = threadIdx.x;
  int sl  = tid & 3;
  int q   = blockIdx.x*64 + (tid >> 2);    // q = b*512 + d
  int d   = q & 511;
  int b   = q >> 9;
  float4 Alr = *(const float4*)(Alog + d*16 + sl*4);
  float A0 = -__expf(Alr.x), A1 = -__expf(Alr.y);
  float A2 = -__expf(Alr.z), A3 = -__expf(Alr.w);
  float Dv = Dpw[d];
  float4 cr = *(const float4*)(cw + d*4);
  float cbv = cb[d];
  float h0=0.f, h1=0.f, h2=0.f, h3=0.f;
  float xm1=0.f, xm2=0.f, xm3=0.f;
  const float* dtp = dtT + (size_t)q*256;
  const float* xip = xiT + (size_t)q*256;
  const unsigned short* zsp = zsT + (size_t)q*256;
  unsigned short* yap = ya + (size_t)b*256*DM + d;
  const float* Bp = Bc + (size_t)b*4096 + sl*4;
  const float* Cp = Cc + (size_t)b*4096 + sl*4;
  #pragma unroll 2
  for (int t0=0; t0<256; t0+=4){
    float4 dt4 = *(const float4*)(dtp + t0);
    float4 xi4 = *(const float4*)(xip + t0);
    uint2  zz  = *(const uint2*)(zsp + t0);
    float xts[4] = {xi4.x, xi4.y, xi4.z, xi4.w};
    float dvs[4] = {dt4.x, dt4.y, dt4.z, dt4.w};
    float zsf[4] = { bfu((unsigned short)zz.x), bfu((unsigned short)(zz.x>>16)),
                     bfu((unsigned short)zz.y), bfu((unsigned short)(zz.y>>16)) };
    #pragma unroll
    for (int r=0;r<4;r++){
      float4 Bv = *(const float4*)(Bp + (t0+r)*16);
      float4 Cv = *(const float4*)(Cp + (t0+r)*16);
      float a  = cbv + xm3*cr.x + xm2*cr.y + xm1*cr.z + xts[r]*cr.w;
      float u  = silu(a);
      float dv = dvs[r];
      float du = dv*u;
      h0 = __expf(dv*A0)*h0 + du*Bv.x;
      h1 = __expf(dv*A1)*h1 + du*Bv.y;
      h2 = __expf(dv*A2)*h2 + du*Bv.z;
      h3 = __expf(dv*A3)*h3 + du*Bv.w;
      float yy = h0*Cv.x + h1*Cv.y + h2*Cv.z + h3*Cv.w;
      yy += __shfl_xor(yy, 1);
      yy += __shfl_xor(yy, 2);
      if (sl == 0) yap[(size_t)(t0+r)*DM] = f2bf((yy + u*Dv) * zsf[r]);
      xm3 = xm2; xm2 = xm1; xm1 = xts[r];
    }
  }
}

// ---------------- K5: out = LayerNorm(o + slots) (f32) ----------------------
__global__ __launch_bounds__(64) void k_fln(const float* __restrict__ o,
                                            const float* __restrict__ resid,
                                            const float* __restrict__ g,
                                            const float* __restrict__ b,
                                            float* __restrict__ out){
  int tok  = blockIdx.x;
  int lane = threadIdx.x;
  const float* row = o     + (size_t)tok*DM + lane*8;
  const float* rr  = resid + (size_t)tok*DM + lane*8;
  float4 r0 = *(const float4*)row;
  float4 r1 = *(const float4*)(row + 4);
  float4 s0 = *(const float4*)rr;
  float4 s1 = *(const float4*)(rr + 4);
  float v[8] = {r0.x+s0.x, r0.y+s0.y, r0.z+s0.z, r0.w+s0.w,
                r1.x+s1.x, r1.y+s1.y, r1.z+s1.z, r1.w+s1.w};
  float s = 0.f;
  #pragma unroll
  for (int i=0;i<8;i++) s += v[i];
  #pragma unroll
  for (int o2=32;o2;o2>>=1) s += __shfl_xor(s, o2, 64);
  float m = s * (1.0f/512.0f);
  float vs = 0.f;
  #pragma unroll
  for (int i=0;i<8;i++){ float d = v[i]-m; vs += d*d; }
  #pragma unroll
  for (int o2=32;o2;o2>>=1) vs += __shfl_xor(vs, o2, 64);
  float rs = rsqrtf(vs*(1.0f/512.0f) + 1e-5f);
  float4 g0 = *(const float4*)(g + lane*8);
  float4 g1 = *(const float4*)(g + lane*8 + 4);
  float4 b0 = *(const float4*)(b + lane*8);
  float4 b1 = *(const float4*)(b + lane*8 + 4);
  float gv[8] = {g0.x,g0.y,g0.z,g0.w, g1.x,g1.y,g1.z,g1.w};
  float bv[8] = {b0.x,b0.y,b0.z,b0.w, b1.x,b1.y,b1.z,b1.w};
  float o8[8];
  #pragma unroll
  for (int i=0;i<8;i++) o8[i] = (v[i]-m)*rs*gv[i] + bv[i];
  float4* op = (float4*)(out + (size_t)tok*DM + lane*8);
  op[0] = make_float4(o8[0],o8[1],o8[2],o8[3]);
  op[1] = make_float4(o8[4],o8[5],o8[6],o8[7]);
}

extern "C" void kernel_launch(void* const* d_in, const int* in_sizes, int n_in,
                              void* d_out, int out_size, void* d_ws, size_t ws_size,
                              hipStream_t stream) {
  const float* slots     = (const float*)d_in[0];
  const float* ln_g      = (const float*)d_in[1];
  const float* ln_b      = (const float*)d_in[2];
  const float* in_proj_w = (const float*)d_in[3];
  const float* conv_w    = (const float*)d_in[4];
  const float* conv_b    = (const float*)d_in[5];
  const float* x_proj_w  = (const float*)d_in[6];
  const float* dt_proj_w = (const float*)d_in[7];
  const float* dt_proj_b = (const float*)d_in[8];
  const float* A_log     = (const float*)d_in[9];
  const float* Dp        = (const float*)d_in[10];
  const float* out_projw = (const float*)d_in[11];
  const float* fln_g     = (const float*)d_in[12];
  const float* fln_b     = (const float*)d_in[13];
  float* out = (float*)d_out;

  const size_t MB = 1024*1024;
  char* base = (char*)d_ws;
  float*          xiT  = (float*)(base);                    // [0,32MB)
  unsigned short* xlnb = (unsigned short*)(base + 32*MB);   // [32,48MB); reused as yab
  unsigned short* yab  = xlnb;
  unsigned short* zsT  = (unsigned short*)(base + 48*MB);   // [48,64MB); head reused as WbO
  unsigned short* WbO  = zsT;
  float*          dto  = (float*)(base + 64*MB);            // [64,96MB): WbI -> dtT -> o
  unsigned short* WbI  = (unsigned short*)dto;
  float*          Bc   = (float*)(base + 96*MB);
  float*          Cc   = (float*)(base + 97*MB);

  k_ln   <<<NTOK,           64, 0, stream>>>(slots, ln_g, ln_b, xlnb);
  k_cvtw <<<256,           256, 0, stream>>>(in_proj_w, WbI);          // 1024x512
  k_gemm <<<dim3(512, 8),  256, 0, stream>>>(xlnb, WbI, xiT, zsT, 0);
  k_xproj<<<NTOK/16,       256, 0, stream>>>(xiT, conv_w, conv_b, x_proj_w, dt_proj_w, dt_proj_b,
                                             dto, Bc, Cc);
  k_scan <<<512,           256, 0, stream>>>(dto, xiT, zsT, Bc, Cc, conv_w, conv_b, A_log, Dp, yab);
  k_cvtw <<<128,           256, 0, stream>>>(out_projw, WbO);          // 512x512
  k_gemm <<<dim3(512, 4),  256, 0, stream>>>(yab, WbO, dto, (unsigned short*)0, 1);
  k_fln  <<<NTOK,           64, 0, stream>>>(dto, slots, fln_g, fln_b, out);
}

// Round 8
// 386.908 us; speedup vs baseline: 3.4402x; 1.3333x over previous
//
#include <hip/hip_runtime.h>
#include <hip/hip_bf16.h>

// SlotMamba: B=64, K=256, D_MODEL=512, D_INNER=512, D_STATE=16, D_CONV=4, DT_RANK=32
// NTOK = 16384. Inputs f32, output f32. GEMMs: bf16 MFMA 16x16x32, f32 accum,
// m97-style 128x128 tile, BK=32, double-buffered LDS via async global_load_lds.
// dt/xi/zs use T-layout: [(b*512+d)*256 + t].
//
// ws layout (MB = 2^20):                lifetime
//   xiT  [0,  32MB) f32 T-layout        gemm(in) -> xproj, scan
//   xlnb [32, 48MB) bf16 [t][d]         ln -> gemm(in); reused as yab: scan -> gemm(out)
//   zsT  [48, 64MB) bf16 T-layout       gemm(in) -> scan; head reused as WbO after scan
//   dtT/o[64, 96MB) f32                 head = WbI (cvtw -> gemm(in)); then dtT; then o [t][d]
//   Bc   [96, 97MB), Cc [97, 98MB)      xproj -> scan

#define NTOK 16384
#define DM   512

typedef __attribute__((ext_vector_type(8))) short bf16x8;
typedef __attribute__((ext_vector_type(4))) float f32x4;

__device__ __forceinline__ unsigned short f2bf(float f){
  unsigned int u = __float_as_uint(f);
  u = (u + 0x7fffu + ((u >> 16) & 1u)) >> 16;   // RNE
  return (unsigned short)u;
}
__device__ __forceinline__ float bfu(unsigned short p){ return __uint_as_float(((unsigned int)p) << 16); }
__device__ __forceinline__ unsigned int pk2(float a, float b){
  return (unsigned int)f2bf(a) | ((unsigned int)f2bf(b) << 16);
}
__device__ __forceinline__ float silu(float a){ return a / (1.f + __expf(-a)); }

// async 16B/lane global->LDS: lane l deposits at ldsbase + l*16 (wave-uniform base)
__device__ __forceinline__ void async_cp16(const unsigned short* g, unsigned short* l){
  __builtin_amdgcn_global_load_lds(
      (const __attribute__((address_space(1))) unsigned int*)g,
      (__attribute__((address_space(3))) unsigned int*)l, 16, 0, 0);
}

// ---------------- K0: f32 -> bf16 weight convert ----------------------------
__global__ __launch_bounds__(256) void k_cvtw(const float* __restrict__ W,
                                              unsigned short* __restrict__ Wb){
  int i = (blockIdx.x*256 + threadIdx.x)*8;
  float4 a = *(const float4*)(W+i);
  float4 b = *(const float4*)(W+i+4);
  uint4 st = { pk2(a.x,a.y), pk2(a.z,a.w), pk2(b.x,b.y), pk2(b.z,b.w) };
  *(uint4*)(Wb+i) = st;
}

// ---------------- K1: LayerNorm(slots) -> xlnb (bf16, [t][d]) ---------------
__global__ __launch_bounds__(64) void k_ln(const float* __restrict__ x,
                                           const float* __restrict__ g,
                                           const float* __restrict__ b,
                                           unsigned short* __restrict__ out){
  int tok  = blockIdx.x;
  int lane = threadIdx.x;
  const float* row = x + (size_t)tok*DM + lane*8;
  float4 r0 = *(const float4*)row;
  float4 r1 = *(const float4*)(row + 4);
  float v[8] = {r0.x,r0.y,r0.z,r0.w, r1.x,r1.y,r1.z,r1.w};
  float s = 0.f;
  #pragma unroll
  for (int i=0;i<8;i++) s += v[i];
  #pragma unroll
  for (int o=32;o;o>>=1) s += __shfl_xor(s, o, 64);
  float m = s * (1.0f/512.0f);
  float vs = 0.f;
  #pragma unroll
  for (int i=0;i<8;i++){ float d = v[i]-m; vs += d*d; }
  #pragma unroll
  for (int o=32;o;o>>=1) vs += __shfl_xor(vs, o, 64);
  float rs = rsqrtf(vs*(1.0f/512.0f) + 1e-5f);
  float4 g0 = *(const float4*)(g + lane*8);
  float4 g1 = *(const float4*)(g + lane*8 + 4);
  float4 b0 = *(const float4*)(b + lane*8);
  float4 b1 = *(const float4*)(b + lane*8 + 4);
  float gv[8] = {g0.x,g0.y,g0.z,g0.w, g1.x,g1.y,g1.z,g1.w};
  float bv[8] = {b0.x,b0.y,b0.z,b0.w, b1.x,b1.y,b1.z,b1.w};
  float o8[8];
  #pragma unroll
  for (int i=0;i<8;i++) o8[i] = (v[i]-m)*rs*gv[i] + bv[i];
  uint4 st = { pk2(o8[0],o8[1]), pk2(o8[2],o8[3]), pk2(o8[4],o8[5]), pk2(o8[6],o8[7]) };
  *(uint4*)(out + (size_t)tok*DM + lane*8) = st;
}

// ---------------- K2: 128x128-tile bf16-MFMA GEMM  C = A @ Wb^T -------------
// A [NTOK][512] bf16, Wb [N][512] bf16. Double-buffered As/Bs (BK=32), async
// global_load_lds staging, XOR chunk swizzle (2-way-free frag reads).
// Wave (of 4) computes 64x64: acc[4][4] 16x16 tiles.
// mode 0: nn<512 -> xiT f32 T-layout; nn>=512 -> zsT bf16 silu. mode 1: o [t][d].
__global__ __launch_bounds__(256) void k_gemm(const unsigned short* __restrict__ A,
                                              const unsigned short* __restrict__ Wb,
                                              float* __restrict__ out_f,
                                              unsigned short* __restrict__ out_b,
                                              int mode){
  __shared__ unsigned short As[2][128*32];
  __shared__ unsigned short Bs[2][128*32];
  int t0  = blockIdx.x * 128;
  int n0  = blockIdx.y * 128;
  int tid = threadIdx.x;
  int lane = tid & 63;
  int wv  = tid >> 6;
  int mw  = wv & 1, nw = wv >> 1;
  int m15 = lane & 15, quad = lane >> 4;

  // staging addresses: slab row (lane>>2), chunk XOR-swizzled by row-pair
  int srow   = wv*32 + (lane >> 2);
  int schunk = ((lane & 3) ^ ((lane >> 3) & 3)) * 8;
  const unsigned short* gA = A  + (size_t)(t0 + srow)*DM + schunk;
  const unsigned short* gB = Wb + (size_t)(n0 + srow)*DM + schunk;
  unsigned short* asb0 = &As[0][(wv*32)*32];
  unsigned short* bsb0 = &Bs[0][(wv*32)*32];
  unsigned short* asb1 = &As[1][(wv*32)*32];
  unsigned short* bsb1 = &Bs[1][(wv*32)*32];

  // prologue: stage ks=0 into buffer 0
  async_cp16(gA,         asb0);
  async_cp16(gA + 16*DM, asb0 + 16*32);
  async_cp16(gB,         bsb0);
  async_cp16(gB + 16*DM, bsb0 + 16*32);

  f32x4 acc[4][4];
  #pragma unroll
  for (int rb=0;rb<4;rb++)
    #pragma unroll
    for (int cb=0;cb<4;cb++) acc[rb][cb] = (f32x4){0.f,0.f,0.f,0.f};

  int rdsw = (quad ^ ((m15 >> 1) & 3)) * 8;   // read-side swizzled chunk
  int cur = 0;
  for (int ks = 0; ks < 16; ks++){
    __syncthreads();                           // drains staging for buf cur
    if (ks < 15){
      const unsigned short* nA = gA + (ks+1)*32;
      const unsigned short* nB = gB + (ks+1)*32;
      unsigned short* na = cur ? asb0 : asb1;
      unsigned short* nb = cur ? bsb0 : bsb1;
      async_cp16(nA,         na);
      async_cp16(nA + 16*DM, na + 16*32);
      async_cp16(nB,         nb);
      async_cp16(nB + 16*DM, nb + 16*32);
    }
    bf16x8 af[4], bfr[4];
    #pragma unroll
    for (int rb=0;rb<4;rb++)
      af[rb] = *(const bf16x8*)&As[cur][(mw*64 + rb*16 + m15)*32 + rdsw];
    #pragma unroll
    for (int cb=0;cb<4;cb++)
      bfr[cb] = *(const bf16x8*)&Bs[cur][(nw*64 + cb*16 + m15)*32 + rdsw];
    #pragma unroll
    for (int rb=0;rb<4;rb++)
      #pragma unroll
      for (int cb=0;cb<4;cb++)
        acc[rb][cb] = __builtin_amdgcn_mfma_f32_16x16x32_bf16(af[rb], bfr[cb], acc[rb][cb], 0, 0, 0);
    cur ^= 1;
  }

  // epilogue: D row = quad*4+r (token), col = lane&15 (validated mapping)
  #pragma unroll
  for (int rb=0;rb<4;rb++){
    int tok0 = t0 + mw*64 + rb*16 + quad*4;    // 4 consecutive tokens
    int b    = tok0 >> 8;
    int tl0  = tok0 & 255;
    #pragma unroll
    for (int cb=0;cb<4;cb++){
      int nn = n0 + nw*64 + cb*16 + m15;
      f32x4 v = acc[rb][cb];
      if (mode == 0){
        if (nn < DM){
          *(f32x4*)(out_f + ((size_t)(b*DM + nn))*256 + tl0) = v;
        } else {
          uint2 z2 = { pk2(silu(v[0]), silu(v[1])), pk2(silu(v[2]), silu(v[3])) };
          *(uint2*)(out_b + ((size_t)(b*DM + (nn - DM)))*256 + tl0) = z2;
        }
      } else {
        #pragma unroll
        for (int r=0;r<4;r++) out_f[(size_t)(tok0+r)*DM + nn] = v[r];
      }
    }
  }
}

// -------- K3: conv4+silu (T-layout reads) ; proj ; dt -> dtT ----------------
__global__ __launch_bounds__(256) void k_xproj(const float* __restrict__ xiT,
                                               const float* __restrict__ cw,
                                               const float* __restrict__ cb,
                                               const float* __restrict__ xpw,
                                               const float* __restrict__ dtw,
                                               const float* __restrict__ dtb,
                                               float* __restrict__ dtT,
                                               float* __restrict__ Bc,
                                               float* __restrict__ Cc){
  __shared__ __align__(16) float xs[16*DM];
  __shared__ __align__(16) float pj[16*64];
  int t0  = blockIdx.x * 16;
  int b   = t0 >> 8;
  int tl0 = t0 & 255;
  int tid = threadIdx.x;

  #pragma unroll
  for (int j=0;j<2;j++){
    int d = tid + 256*j;
    float4 cr = *(const float4*)(cw + d*4);
    float a0 = cb[d];
    const float* row = xiT + ((size_t)(b*DM + d))*256;
    float w[20];
    if (tl0 == 0){
      w[0]=w[1]=w[2]=w[3]=0.f;
      #pragma unroll
      for (int q=0;q<4;q++){
        float4 v4 = *(const float4*)(row + q*4);
        w[4+q*4]=v4.x; w[5+q*4]=v4.y; w[6+q*4]=v4.z; w[7+q*4]=v4.w;
      }
    } else {
      const float* p4 = row + tl0 - 4;
      #pragma unroll
      for (int q=0;q<5;q++){
        float4 v4 = *(const float4*)(p4 + q*4);
        w[q*4]=v4.x; w[1+q*4]=v4.y; w[2+q*4]=v4.z; w[3+q*4]=v4.w;
      }
    }
    #pragma unroll
    for (int t=0;t<16;t++){
      float a = a0 + w[t+1]*cr.x + w[t+2]*cr.y + w[t+3]*cr.z + w[t+4]*cr.w;
      xs[t*DM + d] = silu(a);
    }
  }
  __syncthreads();

  int n = tid & 63, grp = tid >> 6;
  const float* wr = xpw + (size_t)n*DM;
  float a[4] = {0.f,0.f,0.f,0.f};
  for (int k=0;k<DM;k+=4){
    float4 w4 = *(const float4*)(wr + k);
    #pragma unroll
    for (int q=0;q<4;q++){
      float4 xv = *(const float4*)&xs[(grp*4+q)*DM + k];
      a[q] += xv.x*w4.x + xv.y*w4.y + xv.z*w4.z + xv.w*w4.w;
    }
  }
  #pragma unroll
  for (int q=0;q<4;q++) pj[(grp*4+q)*64 + n] = a[q];
  __syncthreads();

  for (int i=tid; i<16*32; i+=256){
    int tt = i >> 5, c = i & 31;
    float v = pj[tt*64 + 32 + c];
    if (c < 16) Bc[(size_t)(t0+tt)*16 + c]      = v;
    else        Cc[(size_t)(t0+tt)*16 + (c-16)] = v;
  }

  #pragma unroll
  for (int jn=0;jn<2;jn++){
    int nn = tid + 256*jn;
    const float* dr = dtw + (size_t)nn*32;
    float wv[32];
    #pragma unroll
    for (int r=0;r<32;r+=4){
      float4 t4 = *(const float4*)(dr + r);
      wv[r]=t4.x; wv[r+1]=t4.y; wv[r+2]=t4.z; wv[r+3]=t4.w;
    }
    float bb = dtb[nn];
    float dts[16];
    #pragma unroll
    for (int tt=0;tt<16;tt++){
      const float* pr = &pj[tt*64];
      float s = bb;
      #pragma unroll
      for (int r=0;r<32;r++) s += pr[r]*wv[r];
      dts[tt] = (s > 20.f) ? s : log1pf(__expf(s));
    }
    float* dst = dtT + ((size_t)(b*DM + nn))*256 + tl0;
    #pragma unroll
    for (int q=0;q<4;q++)
      *(float4*)(dst + q*4) = make_float4(dts[q*4],dts[q*4+1],dts[q*4+2],dts[q*4+3]);
  }
}

// ------ K4: scan, 4 lanes x 4 states per (b,d); T-layout float4 streams -----
__global__ __launch_bounds__(256) void k_scan(const float* __restrict__ dtT,
                                              const float* __restrict__ xiT,
                                              const unsigned short* __restrict__ zsT,
                                              const float* __restrict__ Bc,
                                              const float* __restrict__ Cc,
                                              const float* __restrict__ cw,
                                              const float* __restrict__ cb,
                                              const float* __restrict__ Alog,
                                              const float* __restrict__ Dpw,
                                              unsigned short* __restrict__ ya){
  int tid = threadIdx.x;
  int sl  = tid & 3;
  int q   = blockIdx.x*64 + (tid >> 2);
  int d   = q & 511;
  int b   = q >> 9;
  float4 Alr = *(const float4*)(Alog + d*16 + sl*4);
  float A0 = -__expf(Alr.x), A1 = -__expf(Alr.y);
  float A2 = -__expf(Alr.z), A3 = -__expf(Alr.w);
  float Dv = Dpw[d];
  float4 cr = *(const float4*)(cw + d*4);
  float cbv = cb[d];
  float h0=0.f, h1=0.f, h2=0.f, h3=0.f;
  float xm1=0.f, xm2=0.f, xm3=0.f;
  const float* dtp = dtT + (size_t)q*256;
  const float* xip = xiT + (size_t)q*256;
  const unsigned short* zsp = zsT + (size_t)q*256;
  unsigned short* yap = ya + (size_t)b*256*DM + d;
  const float* Bp = Bc + (size_t)b*4096 + sl*4;
  const float* Cp = Cc + (size_t)b*4096 + sl*4;
  #pragma unroll 2
  for (int t0=0; t0<256; t0+=4){
    float4 dt4 = *(const float4*)(dtp + t0);
    float4 xi4 = *(const float4*)(xip + t0);
    uint2  zz  = *(const uint2*)(zsp + t0);
    float xts[4] = {xi4.x, xi4.y, xi4.z, xi4.w};
    float dvs[4] = {dt4.x, dt4.y, dt4.z, dt4.w};
    float zsf[4] = { bfu((unsigned short)zz.x), bfu((unsigned short)(zz.x>>16)),
                     bfu((unsigned short)zz.y), bfu((unsigned short)(zz.y>>16)) };
    #pragma unroll
    for (int r=0;r<4;r++){
      float4 Bv = *(const float4*)(Bp + (t0+r)*16);
      float4 Cv = *(const float4*)(Cp + (t0+r)*16);
      float a  = cbv + xm3*cr.x + xm2*cr.y + xm1*cr.z + xts[r]*cr.w;
      float u  = silu(a);
      float dv = dvs[r];
      float du = dv*u;
      h0 = __expf(dv*A0)*h0 + du*Bv.x;
      h1 = __expf(dv*A1)*h1 + du*Bv.y;
      h2 = __expf(dv*A2)*h2 + du*Bv.z;
      h3 = __expf(dv*A3)*h3 + du*Bv.w;
      float yy = h0*Cv.x + h1*Cv.y + h2*Cv.z + h3*Cv.w;
      yy += __shfl_xor(yy, 1);
      yy += __shfl_xor(yy, 2);
      if (sl == 0) yap[(size_t)(t0+r)*DM] = f2bf((yy + u*Dv) * zsf[r]);
      xm3 = xm2; xm2 = xm1; xm1 = xts[r];
    }
  }
}

// ---------------- K5: out = LayerNorm(o + slots) (f32) ----------------------
__global__ __launch_bounds__(64) void k_fln(const float* __restrict__ o,
                                            const float* __restrict__ resid,
                                            const float* __restrict__ g,
                                            const float* __restrict__ b,
                                            float* __restrict__ out){
  int tok  = blockIdx.x;
  int lane = threadIdx.x;
  const float* row = o     + (size_t)tok*DM + lane*8;
  const float* rr  = resid + (size_t)tok*DM + lane*8;
  float4 r0 = *(const float4*)row;
  float4 r1 = *(const float4*)(row + 4);
  float4 s0 = *(const float4*)rr;
  float4 s1 = *(const float4*)(rr + 4);
  float v[8] = {r0.x+s0.x, r0.y+s0.y, r0.z+s0.z, r0.w+s0.w,
                r1.x+s1.x, r1.y+s1.y, r1.z+s1.z, r1.w+s1.w};
  float s = 0.f;
  #pragma unroll
  for (int i=0;i<8;i++) s += v[i];
  #pragma unroll
  for (int o2=32;o2;o2>>=1) s += __shfl_xor(s, o2, 64);
  float m = s * (1.0f/512.0f);
  float vs = 0.f;
  #pragma unroll
  for (int i=0;i<8;i++){ float d = v[i]-m; vs += d*d; }
  #pragma unroll
  for (int o2=32;o2;o2>>=1) vs += __shfl_xor(vs, o2, 64);
  float rs = rsqrtf(vs*(1.0f/512.0f) + 1e-5f);
  float4 g0 = *(const float4*)(g + lane*8);
  float4 g1 = *(const float4*)(g + lane*8 + 4);
  float4 b0 = *(const float4*)(b + lane*8);
  float4 b1 = *(const float4*)(b + lane*8 + 4);
  float gv[8] = {g0.x,g0.y,g0.z,g0.w, g1.x,g1.y,g1.z,g1.w};
  float bv[8] = {b0.x,b0.y,b0.z,b0.w, b1.x,b1.y,b1.z,b1.w};
  float o8[8];
  #pragma unroll
  for (int i=0;i<8;i++) o8[i] = (v[i]-m)*rs*gv[i] + bv[i];
  float4* op = (float4*)(out + (size_t)tok*DM + lane*8);
  op[0] = make_float4(o8[0],o8[1],o8[2],o8[3]);
  op[1] = make_float4(o8[4],o8[5],o8[6],o8[7]);
}

extern "C" void kernel_launch(void* const* d_in, const int* in_sizes, int n_in,
                              void* d_out, int out_size, void* d_ws, size_t ws_size,
                              hipStream_t stream) {
  const float* slots     = (const float*)d_in[0];
  const float* ln_g      = (const float*)d_in[1];
  const float* ln_b      = (const float*)d_in[2];
  const float* in_proj_w = (const float*)d_in[3];
  const float* conv_w    = (const float*)d_in[4];
  const float* conv_b    = (const float*)d_in[5];
  const float* x_proj_w  = (const float*)d_in[6];
  const float* dt_proj_w = (const float*)d_in[7];
  const float* dt_proj_b = (const float*)d_in[8];
  const float* A_log     = (const float*)d_in[9];
  const float* Dp        = (const float*)d_in[10];
  const float* out_projw = (const float*)d_in[11];
  const float* fln_g     = (const float*)d_in[12];
  const float* fln_b     = (const float*)d_in[13];
  float* out = (float*)d_out;

  const size_t MB = 1024*1024;
  char* base = (char*)d_ws;
  float*          xiT  = (float*)(base);                    // [0,32MB)
  unsigned short* xlnb = (unsigned short*)(base + 32*MB);   // [32,48MB); reused as yab
  unsigned short* yab  = xlnb;
  unsigned short* zsT  = (unsigned short*)(base + 48*MB);   // [48,64MB); head reused as WbO
  unsigned short* WbO  = zsT;
  float*          dto  = (float*)(base + 64*MB);            // [64,96MB): WbI -> dtT -> o
  unsigned short* WbI  = (unsigned short*)dto;
  float*          Bc   = (float*)(base + 96*MB);
  float*          Cc   = (float*)(base + 97*MB);

  k_ln   <<<NTOK,           64, 0, stream>>>(slots, ln_g, ln_b, xlnb);
  k_cvtw <<<256,           256, 0, stream>>>(in_proj_w, WbI);          // 1024x512
  k_gemm <<<dim3(128, 8),  256, 0, stream>>>(xlnb, WbI, xiT, zsT, 0);
  k_xproj<<<NTOK/16,       256, 0, stream>>>(xiT, conv_w, conv_b, x_proj_w, dt_proj_w, dt_proj_b,
                                             dto, Bc, Cc);
  k_scan <<<512,           256, 0, stream>>>(dto, xiT, zsT, Bc, Cc, conv_w, conv_b, A_log, Dp, yab);
  k_cvtw <<<128,           256, 0, stream>>>(out_projw, WbO);          // 512x512
  k_gemm <<<dim3(128, 4),  256, 0, stream>>>(yab, WbO, dto, (unsigned short*)0, 1);
  k_fln  <<<NTOK,           64, 0, stream>>>(dto, slots, fln_g, fln_b, out);
}

// Round 9
// 319.623 us; speedup vs baseline: 4.1644x; 1.2105x over previous
//
#include <hip/hip_runtime.h>
#include <hip/hip_bf16.h>

// SlotMamba: B=64, K=256, D_MODEL=512, D_INNER=512, D_STATE=16, D_CONV=4, DT_RANK=32
// NTOK = 16384. Inputs f32, output f32. All three GEMMs (in_proj, x_proj+dt_proj,
// out_proj) run as bf16 MFMA 16x16x32 with f32 accum.
// dt/xi/zs use T-layout: [(b*512+d)*256 + t].
//
// ws layout (MB = 2^20):                lifetime
//   xiT  [0,  32MB) f32 T-layout        gemm(in) -> xproj, scan
//   xlnb [32, 48MB) bf16 [t][d]         ln -> gemm(in); head reused as xpwb/dtwb (cvtw -> xproj);
//                                       whole region reused as yab: scan -> gemm(out)
//   zsT  [48, 64MB) bf16 T-layout       gemm(in) -> scan; head reused as WbO after scan
//   dtT/o[64, 96MB) f32                 head = WbI (cvtw -> gemm(in)); then dtT; then o [t][d]
//   Bc   [96, 97MB), Cc [97, 98MB)      xproj -> scan

#define NTOK 16384
#define DM   512

typedef __attribute__((ext_vector_type(8))) short bf16x8;
typedef __attribute__((ext_vector_type(4))) float f32x4;

__device__ __forceinline__ unsigned short f2bf(float f){
  unsigned int u = __float_as_uint(f);
  u = (u + 0x7fffu + ((u >> 16) & 1u)) >> 16;   // RNE
  return (unsigned short)u;
}
__device__ __forceinline__ float bfu(unsigned short p){ return __uint_as_float(((unsigned int)p) << 16); }
__device__ __forceinline__ unsigned int pk2(float a, float b){
  return (unsigned int)f2bf(a) | ((unsigned int)f2bf(b) << 16);
}
__device__ __forceinline__ float silu(float a){ return a / (1.f + __expf(-a)); }

// async 16B/lane global->LDS: lane l deposits at ldsbase + l*16 (wave-uniform base)
__device__ __forceinline__ void async_cp16(const unsigned short* g, unsigned short* l){
  __builtin_amdgcn_global_load_lds(
      (const __attribute__((address_space(1))) unsigned int*)g,
      (__attribute__((address_space(3))) unsigned int*)l, 16, 0, 0);
}

// ---------------- K0: f32 -> bf16 weight convert ----------------------------
__global__ __launch_bounds__(256) void k_cvtw(const float* __restrict__ W,
                                              unsigned short* __restrict__ Wb){
  int i = (blockIdx.x*256 + threadIdx.x)*8;
  float4 a = *(const float4*)(W+i);
  float4 b = *(const float4*)(W+i+4);
  uint4 st = { pk2(a.x,a.y), pk2(a.z,a.w), pk2(b.x,b.y), pk2(b.z,b.w) };
  *(uint4*)(Wb+i) = st;
}

// ---------------- K1: LayerNorm(slots) -> xlnb (bf16, [t][d]) ---------------
__global__ __launch_bounds__(64) void k_ln(const float* __restrict__ x,
                                           const float* __restrict__ g,
                                           const float* __restrict__ b,
                                           unsigned short* __restrict__ out){
  int tok  = blockIdx.x;
  int lane = threadIdx.x;
  const float* row = x + (size_t)tok*DM + lane*8;
  float4 r0 = *(const float4*)row;
  float4 r1 = *(const float4*)(row + 4);
  float v[8] = {r0.x,r0.y,r0.z,r0.w, r1.x,r1.y,r1.z,r1.w};
  float s = 0.f;
  #pragma unroll
  for (int i=0;i<8;i++) s += v[i];
  #pragma unroll
  for (int o=32;o;o>>=1) s += __shfl_xor(s, o, 64);
  float m = s * (1.0f/512.0f);
  float vs = 0.f;
  #pragma unroll
  for (int i=0;i<8;i++){ float d = v[i]-m; vs += d*d; }
  #pragma unroll
  for (int o=32;o;o>>=1) vs += __shfl_xor(vs, o, 64);
  float rs = rsqrtf(vs*(1.0f/512.0f) + 1e-5f);
  float4 g0 = *(const float4*)(g + lane*8);
  float4 g1 = *(const float4*)(g + lane*8 + 4);
  float4 b0 = *(const float4*)(b + lane*8);
  float4 b1 = *(const float4*)(b + lane*8 + 4);
  float gv[8] = {g0.x,g0.y,g0.z,g0.w, g1.x,g1.y,g1.z,g1.w};
  float bv[8] = {b0.x,b0.y,b0.z,b0.w, b1.x,b1.y,b1.z,b1.w};
  float o8[8];
  #pragma unroll
  for (int i=0;i<8;i++) o8[i] = (v[i]-m)*rs*gv[i] + bv[i];
  uint4 st = { pk2(o8[0],o8[1]), pk2(o8[2],o8[3]), pk2(o8[4],o8[5]), pk2(o8[6],o8[7]) };
  *(uint4*)(out + (size_t)tok*DM + lane*8) = st;
}

// ---------------- K2: 128x128-tile bf16-MFMA GEMM  C = A @ Wb^T -------------
__global__ __launch_bounds__(256) void k_gemm(const unsigned short* __restrict__ A,
                                              const unsigned short* __restrict__ Wb,
                                              float* __restrict__ out_f,
                                              unsigned short* __restrict__ out_b,
                                              int mode){
  __shared__ unsigned short As[2][128*32];
  __shared__ unsigned short Bs[2][128*32];
  int t0  = blockIdx.x * 128;
  int n0  = blockIdx.y * 128;
  int tid = threadIdx.x;
  int lane = tid & 63;
  int wv  = tid >> 6;
  int mw  = wv & 1, nw = wv >> 1;
  int m15 = lane & 15, quad = lane >> 4;

  int srow   = wv*32 + (lane >> 2);
  int schunk = ((lane & 3) ^ ((lane >> 3) & 3)) * 8;
  const unsigned short* gA = A  + (size_t)(t0 + srow)*DM + schunk;
  const unsigned short* gB = Wb + (size_t)(n0 + srow)*DM + schunk;
  unsigned short* asb0 = &As[0][(wv*32)*32];
  unsigned short* bsb0 = &Bs[0][(wv*32)*32];
  unsigned short* asb1 = &As[1][(wv*32)*32];
  unsigned short* bsb1 = &Bs[1][(wv*32)*32];

  async_cp16(gA,         asb0);
  async_cp16(gA + 16*DM, asb0 + 16*32);
  async_cp16(gB,         bsb0);
  async_cp16(gB + 16*DM, bsb0 + 16*32);

  f32x4 acc[4][4];
  #pragma unroll
  for (int rb=0;rb<4;rb++)
    #pragma unroll
    for (int cb=0;cb<4;cb++) acc[rb][cb] = (f32x4){0.f,0.f,0.f,0.f};

  int rdsw = (quad ^ ((m15 >> 1) & 3)) * 8;
  int cur = 0;
  for (int ks = 0; ks < 16; ks++){
    __syncthreads();
    if (ks < 15){
      const unsigned short* nA = gA + (ks+1)*32;
      const unsigned short* nB = gB + (ks+1)*32;
      unsigned short* na = cur ? asb0 : asb1;
      unsigned short* nb = cur ? bsb0 : bsb1;
      async_cp16(nA,         na);
      async_cp16(nA + 16*DM, na + 16*32);
      async_cp16(nB,         nb);
      async_cp16(nB + 16*DM, nb + 16*32);
    }
    bf16x8 af[4], bfr[4];
    #pragma unroll
    for (int rb=0;rb<4;rb++)
      af[rb] = *(const bf16x8*)&As[cur][(mw*64 + rb*16 + m15)*32 + rdsw];
    #pragma unroll
    for (int cb=0;cb<4;cb++)
      bfr[cb] = *(const bf16x8*)&Bs[cur][(nw*64 + cb*16 + m15)*32 + rdsw];
    #pragma unroll
    for (int rb=0;rb<4;rb++)
      #pragma unroll
      for (int cb=0;cb<4;cb++)
        acc[rb][cb] = __builtin_amdgcn_mfma_f32_16x16x32_bf16(af[rb], bfr[cb], acc[rb][cb], 0, 0, 0);
    cur ^= 1;
  }

  #pragma unroll
  for (int rb=0;rb<4;rb++){
    int tok0 = t0 + mw*64 + rb*16 + quad*4;
    int b    = tok0 >> 8;
    int tl0  = tok0 & 255;
    #pragma unroll
    for (int cb=0;cb<4;cb++){
      int nn = n0 + nw*64 + cb*16 + m15;
      f32x4 v = acc[rb][cb];
      if (mode == 0){
        if (nn < DM){
          *(f32x4*)(out_f + ((size_t)(b*DM + nn))*256 + tl0) = v;
        } else {
          uint2 z2 = { pk2(silu(v[0]), silu(v[1])), pk2(silu(v[2]), silu(v[3])) };
          *(uint2*)(out_b + ((size_t)(b*DM + (nn - DM)))*256 + tl0) = z2;
        }
      } else {
        #pragma unroll
        for (int r=0;r<4;r++) out_f[(size_t)(tok0+r)*DM + nn] = v[r];
      }
    }
  }
}

// -------- K3 (MFMA): conv4+silu -> bf16 A-tile; proj & dt via MFMA ----------
// 32 tokens/block (512 blocks). proj: M=32,N=64,K=512; dt: M=32,N=512,K=32.
__global__ __launch_bounds__(256) void k_xproj(const float* __restrict__ xiT,
                                               const float* __restrict__ cw,
                                               const float* __restrict__ cb,
                                               const unsigned short* __restrict__ xpwb,
                                               const unsigned short* __restrict__ dtwb,
                                               const float* __restrict__ dtb,
                                               float* __restrict__ dtT,
                                               float* __restrict__ Bc,
                                               float* __restrict__ Cc){
  __shared__ unsigned short xcb[32*520];      // conv+silu tile, bf16, stride 520
  __shared__ unsigned short Bst[2][64*32];    // xpw k-slab double buffer (XOR swizzled)
  __shared__ unsigned short pjA[32*40];       // dtr bf16, A-frag layout, +8 pad
  int t0  = blockIdx.x * 32;
  int b   = t0 >> 8;
  int tl0 = t0 & 255;
  int tid = threadIdx.x;
  int lane = tid & 63;
  int wv  = tid >> 6;
  int m15 = lane & 15, quad = lane >> 4;

  // ---- conv4 + silu -> xcb ----
  #pragma unroll
  for (int j=0;j<2;j++){
    int d = tid + 256*j;
    float4 cr = *(const float4*)(cw + d*4);
    float a0 = cb[d];
    const float* row = xiT + ((size_t)(b*DM + d))*256;
    float w[36];
    if (tl0 == 0){
      w[0]=w[1]=w[2]=w[3]=0.f;
      #pragma unroll
      for (int q2=0;q2<8;q2++){
        float4 v4 = *(const float4*)(row + q2*4);
        w[4+q2*4]=v4.x; w[5+q2*4]=v4.y; w[6+q2*4]=v4.z; w[7+q2*4]=v4.w;
      }
    } else {
      const float* p4 = row + tl0 - 4;
      #pragma unroll
      for (int q2=0;q2<9;q2++){
        float4 v4 = *(const float4*)(p4 + q2*4);
        w[q2*4]=v4.x; w[1+q2*4]=v4.y; w[2+q2*4]=v4.z; w[3+q2*4]=v4.w;
      }
    }
    #pragma unroll
    for (int t=0;t<32;t++){
      float a = a0 + w[t+1]*cr.x + w[t+2]*cr.y + w[t+3]*cr.z + w[t+4]*cr.w;
      xcb[t*520 + d] = f2bf(silu(a));
    }
  }

  // stage ks=0 of xpw (64 rows x 32 k), XOR chunk swizzle
  int srow = wv*16 + (lane >> 2);
  int sch  = ((lane & 3) ^ ((lane >> 3) & 3)) * 8;
  async_cp16(xpwb + srow*DM + sch, &Bst[0][(wv*16)*32]);
  __syncthreads();                 // xcb ready + stage0 drained

  // ---- proj MFMA: wave = (m-tile mt, nt-pair ntp) ----
  int mt = wv & 1, ntp = wv >> 1;
  f32x4 pacc[2];
  pacc[0] = (f32x4){0.f,0.f,0.f,0.f};
  pacc[1] = (f32x4){0.f,0.f,0.f,0.f};
  int rdsw = (quad ^ ((m15 >> 1) & 3)) * 8;
  int cur = 0;
  for (int ks=0; ks<16; ks++){
    if (ks < 15)
      async_cp16(xpwb + srow*DM + (ks+1)*32 + sch, &Bst[cur^1][(wv*16)*32]);
    bf16x8 af = *(const bf16x8*)&xcb[(mt*16 + m15)*520 + ks*32 + quad*8];
    #pragma unroll
    for (int j2=0;j2<2;j2++){
      int nt = ntp*2 + j2;
      bf16x8 bfr = *(const bf16x8*)&Bst[cur][(nt*16 + m15)*32 + rdsw];
      pacc[j2] = __builtin_amdgcn_mfma_f32_16x16x32_bf16(af, bfr, pacc[j2], 0, 0, 0);
    }
    cur ^= 1;
    __syncthreads();               // next slab staged; prev reads done
  }

  // dtr (cols 0..31) -> pjA (bf16, A-frag layout); cols 32..63 -> Bc/Cc
  if (ntp == 0){
    #pragma unroll
    for (int j2=0;j2<2;j2++){
      int col = j2*16 + m15;
      #pragma unroll
      for (int r=0;r<4;r++)
        pjA[(mt*16 + quad*4 + r)*40 + col] = f2bf(pacc[j2][r]);
    }
  } else {
    #pragma unroll
    for (int j2=0;j2<2;j2++){
      int c = j2*16 + m15;
      #pragma unroll
      for (int r=0;r<4;r++){
        int tt = t0 + mt*16 + quad*4 + r;
        float v = pacc[j2][r];
        if (c < 16) Bc[(size_t)tt*16 + c] = v;
        else        Cc[(size_t)tt*16 + (c-16)] = v;
      }
    }
  }
  __syncthreads();

  // ---- dt MFMA: M=32 (mt), N=512 split 2 waves x 16 n-tiles, K=32 ----
  bf16x8 adt = *(const bf16x8*)&pjA[(mt*16 + m15)*40 + quad*8];
  int nh = wv >> 1;
  #pragma unroll
  for (int j2=0;j2<16;j2++){
    int nn = (nh*16 + j2)*16 + m15;
    bf16x8 bfr = *(const bf16x8*)(dtwb + nn*32 + quad*8);
    f32x4 dacc = (f32x4){0.f,0.f,0.f,0.f};
    dacc = __builtin_amdgcn_mfma_f32_16x16x32_bf16(adt, bfr, dacc, 0, 0, 0);
    float bb = dtb[nn];
    f32x4 o;
    #pragma unroll
    for (int r=0;r<4;r++){
      float s = dacc[r] + bb;
      o[r] = (s > 20.f) ? s : log1pf(__expf(s));
    }
    *(f32x4*)(dtT + ((size_t)(b*DM + nn))*256 + tl0 + mt*16 + quad*4) = o;
  }
}

// ------ K4: scan, 4 lanes x 4 states per (b,d); T-layout float4 streams -----
__global__ __launch_bounds__(256) void k_scan(const float* __restrict__ dtT,
                                              const float* __restrict__ xiT,
                                              const unsigned short* __restrict__ zsT,
                                              const float* __restrict__ Bc,
                                              const float* __restrict__ Cc,
                                              const float* __restrict__ cw,
                                              const float* __restrict__ cb,
                                              const float* __restrict__ Alog,
                                              const float* __restrict__ Dpw,
                                              unsigned short* __restrict__ ya){
  int tid = threadIdx.x;
  int sl  = tid & 3;
  int q   = blockIdx.x*64 + (tid >> 2);
  int d   = q & 511;
  int b   = q >> 9;
  float4 Alr = *(const float4*)(Alog + d*16 + sl*4);
  float A0 = -__expf(Alr.x), A1 = -__expf(Alr.y);
  float A2 = -__expf(Alr.z), A3 = -__expf(Alr.w);
  float Dv = Dpw[d];
  float4 cr = *(const float4*)(cw + d*4);
  float cbv = cb[d];
  float h0=0.f, h1=0.f, h2=0.f, h3=0.f;
  float xm1=0.f, xm2=0.f, xm3=0.f;
  const float* dtp = dtT + (size_t)q*256;
  const float* xip = xiT + (size_t)q*256;
  const unsigned short* zsp = zsT + (size_t)q*256;
  unsigned short* yap = ya + (size_t)b*256*DM + d;
  const float* Bp = Bc + (size_t)b*4096 + sl*4;
  const float* Cp = Cc + (size_t)b*4096 + sl*4;
  #pragma unroll 2
  for (int t0=0; t0<256; t0+=4){
    float4 dt4 = *(const float4*)(dtp + t0);
    float4 xi4 = *(const float4*)(xip + t0);
    uint2  zz  = *(const uint2*)(zsp + t0);
    float xts[4] = {xi4.x, xi4.y, xi4.z, xi4.w};
    float dvs[4] = {dt4.x, dt4.y, dt4.z, dt4.w};
    float zsf[4] = { bfu((unsigned short)zz.x), bfu((unsigned short)(zz.x>>16)),
                     bfu((unsigned short)zz.y), bfu((unsigned short)(zz.y>>16)) };
    #pragma unroll
    for (int r=0;r<4;r++){
      float4 Bv = *(const float4*)(Bp + (t0+r)*16);
      float4 Cv = *(const float4*)(Cp + (t0+r)*16);
      float a  = cbv + xm3*cr.x + xm2*cr.y + xm1*cr.z + xts[r]*cr.w;
      float u  = silu(a);
      float dv = dvs[r];
      float du = dv*u;
      h0 = __expf(dv*A0)*h0 + du*Bv.x;
      h1 = __expf(dv*A1)*h1 + du*Bv.y;
      h2 = __expf(dv*A2)*h2 + du*Bv.z;
      h3 = __expf(dv*A3)*h3 + du*Bv.w;
      float yy = h0*Cv.x + h1*Cv.y + h2*Cv.z + h3*Cv.w;
      yy += __shfl_xor(yy, 1);
      yy += __shfl_xor(yy, 2);
      if (sl == 0) yap[(size_t)(t0+r)*DM] = f2bf((yy + u*Dv) * zsf[r]);
      xm3 = xm2; xm2 = xm1; xm1 = xts[r];
    }
  }
}

// ---------------- K5: out = LayerNorm(o + slots) (f32) ----------------------
__global__ __launch_bounds__(64) void k_fln(const float* __restrict__ o,
                                            const float* __restrict__ resid,
                                            const float* __restrict__ g,
                                            const float* __restrict__ b,
                                            float* __restrict__ out){
  int tok  = blockIdx.x;
  int lane = threadIdx.x;
  const float* row = o     + (size_t)tok*DM + lane*8;
  const float* rr  = resid + (size_t)tok*DM + lane*8;
  float4 r0 = *(const float4*)row;
  float4 r1 = *(const float4*)(row + 4);
  float4 s0 = *(const float4*)rr;
  float4 s1 = *(const float4*)(rr + 4);
  float v[8] = {r0.x+s0.x, r0.y+s0.y, r0.z+s0.z, r0.w+s0.w,
                r1.x+s1.x, r1.y+s1.y, r1.z+s1.z, r1.w+s1.w};
  float s = 0.f;
  #pragma unroll
  for (int i=0;i<8;i++) s += v[i];
  #pragma unroll
  for (int o2=32;o2;o2>>=1) s += __shfl_xor(s, o2, 64);
  float m = s * (1.0f/512.0f);
  float vs = 0.f;
  #pragma unroll
  for (int i=0;i<8;i++){ float d = v[i]-m; vs += d*d; }
  #pragma unroll
  for (int o2=32;o2;o2>>=1) vs += __shfl_xor(vs, o2, 64);
  float rs = rsqrtf(vs*(1.0f/512.0f) + 1e-5f);
  float4 g0 = *(const float4*)(g + lane*8);
  float4 g1 = *(const float4*)(g + lane*8 + 4);
  float4 b0 = *(const float4*)(b + lane*8);
  float4 b1 = *(const float4*)(b + lane*8 + 4);
  float gv[8] = {g0.x,g0.y,g0.z,g0.w, g1.x,g1.y,g1.z,g1.w};
  float bv[8] = {b0.x,b0.y,b0.z,b0.w, b1.x,b1.y,b1.z,b1.w};
  float o8[8];
  #pragma unroll
  for (int i=0;i<8;i++) o8[i] = (v[i]-m)*rs*gv[i] + bv[i];
  float4* op = (float4*)(out + (size_t)tok*DM + lane*8);
  op[0] = make_float4(o8[0],o8[1],o8[2],o8[3]);
  op[1] = make_float4(o8[4],o8[5],o8[6],o8[7]);
}

extern "C" void kernel_launch(void* const* d_in, const int* in_sizes, int n_in,
                              void* d_out, int out_size, void* d_ws, size_t ws_size,
                              hipStream_t stream) {
  const float* slots     = (const float*)d_in[0];
  const float* ln_g      = (const float*)d_in[1];
  const float* ln_b      = (const float*)d_in[2];
  const float* in_proj_w = (const float*)d_in[3];
  const float* conv_w    = (const float*)d_in[4];
  const float* conv_b    = (const float*)d_in[5];
  const float* x_proj_w  = (const float*)d_in[6];
  const float* dt_proj_w = (const float*)d_in[7];
  const float* dt_proj_b = (const float*)d_in[8];
  const float* A_log     = (const float*)d_in[9];
  const float* Dp        = (const float*)d_in[10];
  const float* out_projw = (const float*)d_in[11];
  const float* fln_g     = (const float*)d_in[12];
  const float* fln_b     = (const float*)d_in[13];
  float* out = (float*)d_out;

  const size_t MB = 1024*1024;
  char* base = (char*)d_ws;
  float*          xiT  = (float*)(base);                    // [0,32MB)
  unsigned short* xlnb = (unsigned short*)(base + 32*MB);   // [32,48MB)
  unsigned short* yab  = xlnb;                              // scan output (later)
  unsigned short* xpwb = xlnb;                              // 64KB, after gemm(in)
  unsigned short* dtwb = xlnb + 32768;                      // 32KB
  unsigned short* zsT  = (unsigned short*)(base + 48*MB);   // [48,64MB); head reused as WbO
  unsigned short* WbO  = zsT;
  float*          dto  = (float*)(base + 64*MB);            // [64,96MB): WbI -> dtT -> o
  unsigned short* WbI  = (unsigned short*)dto;
  float*          Bc   = (float*)(base + 96*MB);
  float*          Cc   = (float*)(base + 97*MB);

  k_ln   <<<NTOK,           64, 0, stream>>>(slots, ln_g, ln_b, xlnb);
  k_cvtw <<<256,           256, 0, stream>>>(in_proj_w, WbI);          // 1024x512
  k_gemm <<<dim3(128, 8),  256, 0, stream>>>(xlnb, WbI, xiT, zsT, 0);
  k_cvtw <<<16,            256, 0, stream>>>(x_proj_w, xpwb);          // 64x512
  k_cvtw <<<8,             256, 0, stream>>>(dt_proj_w, dtwb);         // 512x32
  k_xproj<<<NTOK/32,       256, 0, stream>>>(xiT, conv_w, conv_b, xpwb, dtwb, dt_proj_b,
                                             dto, Bc, Cc);
  k_scan <<<512,           256, 0, stream>>>(dto, xiT, zsT, Bc, Cc, conv_w, conv_b, A_log, Dp, yab);
  k_cvtw <<<128,           256, 0, stream>>>(out_projw, WbO);          // 512x512
  k_gemm <<<dim3(128, 4),  256, 0, stream>>>(yab, WbO, dto, (unsigned short*)0, 1);
  k_fln  <<<NTOK,           64, 0, stream>>>(dto, slots, fln_g, fln_b, out);
}